// Round 9
// baseline (34360.193 us; speedup 1.0000x reference)
//
#include <hip/hip_runtime.h>
#include <math.h>

// Problem constants (fixed by setup_inputs)
#define NN 4096      // N samples
#define DD 256       // flat endo dim (8 vars * 32)
#define NV 8         // vars
#define VD 32        // per-var dim
#define NB 128       // GJ block size (reg[32]/512-thread diag is the proven config)
#define NBLK (NN/NB) // 32
#define NTRI (NBLK*(NBLK+1)/2)  // 528

// fp32-GEMM output ownership mapping (bank-conflict-free)
#define RMAP(ty,u) ((ty)*4 + (((u)>>2)<<6) + ((u)&3))
#define CMAP(tx,v) ((tx)*4 + (((v)>>2)<<6) + ((v)&3))

typedef __attribute__((ext_vector_type(8))) short bf16x8;
typedef __attribute__((ext_vector_type(4))) float f32x4;

#define AS1(p) ((const __attribute__((address_space(1))) void*)(p))
#define AS3(p) ((__attribute__((address_space(3))) void*)(p))

__device__ __forceinline__ void stage16(const ushort* g, ushort* l){
  __builtin_amdgcn_global_load_lds(AS1(g), AS3(l), 16, 0, 0);
}

__device__ __forceinline__ ushort f2bf(float x){
  uint u = __float_as_uint(x);
  u += 0x7FFFu + ((u >> 16) & 1u);
  return (ushort)(u >> 16);
}
__device__ __forceinline__ float bf2f(ushort h){ return __uint_as_float(((uint)h) << 16); }

// triangular block map: p -> (bi >= bj)
__device__ __forceinline__ void tri_map(int p, int& bi, int& bj){
  int b = (int)((sqrtf(8.0f * (float)p + 1.0f) - 1.0f) * 0.5f);
  while ((b + 1) * (b + 2) / 2 <= p) b++;
  while (b * (b + 1) / 2 > p) b--;
  bi = b; bj = p - b * (b + 1) / 2;
}

// ---------------- helpers ----------------
__device__ __forceinline__ void block_atomic_add(float v, float* red, float* dst){
  #pragma unroll
  for (int off = 32; off > 0; off >>= 1) v += __shfl_down(v, off, 64);
  const int lane = threadIdx.x & 63;
  const int w = threadIdx.x >> 6;
  if (lane == 0) red[w] = v;
  __syncthreads();
  if (threadIdx.x == 0) atomicAdd(dst, red[0] + red[1] + red[2] + red[3]);
  __syncthreads();
}

// ---------------- small utility kernels ----------------
__global__ void k_zero(float* p, int n){
  int i = blockIdx.x * blockDim.x + threadIdx.x;
  if (i < n) p[i] = 0.f;
}

__global__ void k_norms(const float* __restrict__ z, const float* __restrict__ zz,
                        const float* __restrict__ stdn,
                        float* __restrict__ stdsq, float* __restrict__ zrs,
                        float* __restrict__ nzz, float* __restrict__ nz8){
  int t = blockIdx.x * blockDim.x + threadIdx.x;
  if (t >= NN * NV) return;
  int i = t / NV, v = t % NV;
  const float* zp  = z  + (size_t)i * DD + v * VD;
  const float* zzp = zz + (size_t)i * DD + v * VD;
  float s1 = 0.f, s2 = 0.f, s2z = 0.f;
  #pragma unroll
  for (int k = 0; k < VD; k++){
    float a = zp[k];  s1 += a; s2 += a * a;
    float b = zzp[k]; s2z += b * b;
  }
  zrs[(size_t)i * NV + v] = s1;
  nz8[(size_t)v * NN + i] = s2;
  nzz[(size_t)v * NN + i] = s2z;
  if (v == 0){
    float s = 0.f;
    #pragma unroll
    for (int u = 0; u < NV; u++){ float a = stdn[(size_t)i * NV + u]; s += a * a; }
    stdsq[i] = s;
  }
}

__global__ void k_rownorm(const float* __restrict__ nz8, float* __restrict__ nrmz){
  int i = blockIdx.x * blockDim.x + threadIdx.x;
  if (i < NN){
    float s = 0.f;
    #pragma unroll
    for (int v = 0; v < NV; v++) s += nz8[(size_t)v * NN + i];
    nrmz[i] = s;
  }
}

__global__ __launch_bounds__(256) void k_nll(const float* __restrict__ x,
                                             const float* __restrict__ xx,
                                             float* __restrict__ slots){
  __shared__ float red[4];
  float s = 0.f;
  const int total = NN * DD;
  for (int i = (blockIdx.x * 256 + threadIdx.x) * 4; i < total; i += gridDim.x * 256 * 4){
    float4 a = *(const float4*)(x + i);
    float4 b = *(const float4*)(xx + i);
    float d0 = b.x - a.x, d1 = b.y - a.y, d2 = b.z - a.z, d3 = b.w - a.w;
    s += d0*d0 + d1*d1 + d2*d2 + d3*d3;
  }
  block_atomic_add(s, red, slots + 3);
}

// ---------------- first (exo-free) MMD term ----------------
__global__ __launch_bounds__(256) void k_sqq(const float* __restrict__ z,
                                             const float* __restrict__ nrm,
                                             float* __restrict__ slots){
  __shared__ float Xr[128 * 33];
  __shared__ float Xc[128 * 33];
  __shared__ float red[4];
  int bi, bj; tri_map(blockIdx.x, bi, bj);
  const int r0 = bi * 128, c0 = bj * 128;
  const float wgt = (bi != bj) ? 2.f : 1.f;
  const int t = threadIdx.x;
  const int tx = t & 15, ty = t >> 4;
  const int lrow = t >> 1, lh = t & 1;
  float acc[8][8];
  #pragma unroll
  for (int u = 0; u < 8; u++)
    #pragma unroll
    for (int v = 0; v < 8; v++) acc[u][v] = 0.f;
  for (int ks = 0; ks < DD; ks += 32){
    const float* pr = z + (size_t)(r0 + lrow) * DD + ks + lh * 16;
    const float* pc = z + (size_t)(c0 + lrow) * DD + ks + lh * 16;
    float* dr = &Xr[lrow * 33 + lh * 16];
    float* dc = &Xc[lrow * 33 + lh * 16];
    #pragma unroll
    for (int u = 0; u < 4; u++){
      float4 a = ((const float4*)pr)[u];
      dr[4*u+0] = a.x; dr[4*u+1] = a.y; dr[4*u+2] = a.z; dr[4*u+3] = a.w;
      float4 b = ((const float4*)pc)[u];
      dc[4*u+0] = b.x; dc[4*u+1] = b.y; dc[4*u+2] = b.z; dc[4*u+3] = b.w;
    }
    __syncthreads();
    #pragma unroll
    for (int kk = 0; kk < 32; kk++){
      float a[8], b[8];
      #pragma unroll
      for (int u = 0; u < 8; u++) a[u] = Xr[RMAP(ty,u)*33 + kk];
      #pragma unroll
      for (int v = 0; v < 8; v++) b[v] = Xc[CMAP(tx,v)*33 + kk];
      #pragma unroll
      for (int u = 0; u < 8; u++)
        #pragma unroll
        for (int v = 0; v < 8; v++) acc[u][v] += a[u] * b[v];
    }
    __syncthreads();
  }
  float s = 0.f;
  #pragma unroll 1
  for (int u = 0; u < 8; u++){
    const float ni = nrm[r0 + RMAP(ty,u)];
    #pragma unroll 1
    for (int v = 0; v < 8; v++)
      s += __expf(-(ni + nrm[c0 + CMAP(tx,v)] - 2.f * acc[u][v]) * (1.f/2048.f));
  }
  block_atomic_add(s * wgt, red, slots + 0);
}

__global__ __launch_bounds__(256) void k_spp_sqp(const float* __restrict__ stdn,
                                                 const float* __restrict__ stdsq,
                                                 const float* __restrict__ zrs,
                                                 const float* __restrict__ nrmz,
                                                 float* __restrict__ slots){
  __shared__ float sI[128*9], sJ[128*9], zI[128*9];
  __shared__ float qI[128], qJ[128], nI[128];
  __shared__ float red[4];
  const int r0 = blockIdx.y * 128, c0 = blockIdx.x * 128;
  const int t = threadIdx.x;
  if (t < 128){
    #pragma unroll
    for (int v = 0; v < 8; v++){
      sI[t*9+v] = stdn[(size_t)(r0+t)*NV + v];
      sJ[t*9+v] = stdn[(size_t)(c0+t)*NV + v];
      zI[t*9+v] = zrs[(size_t)(r0+t)*NV + v];
    }
    qI[t] = stdsq[r0+t]; qJ[t] = stdsq[c0+t]; nI[t] = nrmz[r0+t];
  }
  __syncthreads();
  const int tx = t & 15, ty = t >> 4;
  float spp = 0.f, sqp = 0.f;
  #pragma unroll 1
  for (int u = 0; u < 8; u++){
    int i = ty + 16*u;
    #pragma unroll 1
    for (int v = 0; v < 8; v++){
      int j = tx + 16*v;
      float dpp = 0.f, dqp = 0.f;
      #pragma unroll
      for (int k = 0; k < 8; k++){
        float sj = sJ[j*9+k];
        dpp += sI[i*9+k] * sj;
        dqp += zI[i*9+k] * sj;
      }
      spp += __expf(-(qI[i] + qJ[j] - 2.f*dpp) * (1.f/64.f));
      sqp += __expf(-(nI[i] + 32.f*qJ[j] - 2.f*dqp) * (1.f/2048.f));
    }
  }
  block_atomic_add(spp, red, slots + 1);
  block_atomic_add(sqp, red, slots + 2);
}

// ---------------- RBF Gram matrix build (K=32) ----------------
__global__ __launch_bounds__(256) void k_rbf(const float* __restrict__ Xr_,
                                             const float* __restrict__ Xc_,
                                             const float* __restrict__ nr,
                                             const float* __restrict__ nc,
                                             float lam, float* __restrict__ M){
  __shared__ float Xr[128 * 33];
  __shared__ float Xc[128 * 33];
  const int r0 = blockIdx.y * 128, c0 = blockIdx.x * 128;
  const int t = threadIdx.x;
  const int tx = t & 15, ty = t >> 4;
  const int lrow = t >> 1, lh = t & 1;
  {
    const float* pr = Xr_ + (size_t)(r0 + lrow) * DD + lh * 16;
    const float* pc = Xc_ + (size_t)(c0 + lrow) * DD + lh * 16;
    float* dr = &Xr[lrow * 33 + lh * 16];
    float* dc = &Xc[lrow * 33 + lh * 16];
    #pragma unroll
    for (int u = 0; u < 4; u++){
      float4 a = ((const float4*)pr)[u];
      dr[4*u+0]=a.x; dr[4*u+1]=a.y; dr[4*u+2]=a.z; dr[4*u+3]=a.w;
      float4 b = ((const float4*)pc)[u];
      dc[4*u+0]=b.x; dc[4*u+1]=b.y; dc[4*u+2]=b.z; dc[4*u+3]=b.w;
    }
  }
  __syncthreads();
  #pragma unroll 1
  for (int u = 0; u < 8; u++){
    const int gi = r0 + RMAP(ty,u);
    const float* xi = &Xr[RMAP(ty,u)*33];
    const float ni = nr[gi];
    float vals[8];
    #pragma unroll 1
    for (int v = 0; v < 8; v++){
      const int gj = c0 + CMAP(tx,v);
      const float* xj = &Xc[CMAP(tx,v)*33];
      float d = 0.f;
      #pragma unroll
      for (int k = 0; k < 32; k++) d += xi[k] * xj[k];
      float e = __expf(-(ni + nc[gj] - 2.f*d) * (1.f/32.f));
      if (gi == gj) e += lam;
      vals[v] = e;
    }
    float* pd = M + (size_t)gi * NN + c0 + tx*4;
    *(float4*)pd        = make_float4(vals[0], vals[1], vals[2], vals[3]);
    *(float4*)(pd + 64) = make_float4(vals[4], vals[5], vals[6], vals[7]);
  }
}

// ---------------- fp32 -> bf16 (hi only; trace GEMMs run pure bf16) ----------------
__global__ __launch_bounds__(256) void k_split(const float* __restrict__ S,
                                               ushort* __restrict__ H){
  size_t i = ((size_t)blockIdx.x * 256 + threadIdx.x) * 4;
  float4 x = *(const float4*)(S + i);
  *(ushort4*)(H + i) = make_ushort4(f2bf(x.x), f2bf(x.y), f2bf(x.z), f2bf(x.w));
}

// ---------------- MFMA bf16 GEMM + fused RBF-trace epilogue(s) + fused tr(L*A) ----
__global__ __launch_bounds__(256) void k_mfma_tr(
    const ushort* __restrict__ Ah, const ushort* __restrict__ Bh,
    int sym, int doRed, int nepi,
    const float* e0xr, const float* e0xc, const float* e0nr, const float* e0nc, int s0, int rs0,
    const float* e1xr, const float* e1xc, const float* e1nr, const float* e1nc, int s1, int rs1,
    float* __restrict__ slots){
  __shared__ __align__(16) float shf[2*128*33 + 4];
  ushort* tAh = (ushort*)shf;
  ushort* tBh = tAh + 4096;
  float* red = shf + 2*128*33;
  int bi, bj;
  if (sym){ tri_map(blockIdx.x, bi, bj); } else { bi = blockIdx.y; bj = blockIdx.x; }
  const int r0 = bi * 128, c0 = bj * 128;
  const float wgt = (sym && bi != bj) ? 2.f : 1.f;
  const int t = threadIdx.x;
  const int L = t & 63, w = t >> 6;
  const int wr = w >> 1, wc = w & 1;
  const int lm = L & 15, quad = L >> 4;
  const int sch = (t & 3) * 8;

  f32x4 acc[4][4];
  #pragma unroll
  for (int i = 0; i < 4; i++)
    #pragma unroll
    for (int j = 0; j < 4; j++) acc[i][j] = (f32x4){0.f, 0.f, 0.f, 0.f};

  for (int ks = 0; ks < NN; ks += 32){
    #pragma unroll
    for (int p = 0; p < 2; p++){
      const int row = p*64 + (t >> 2);
      const size_t ga = (size_t)(r0 + row) * NN + ks + sch;
      const size_t gb = (size_t)(c0 + row) * NN + ks + sch;
      const int lo = row*32 + sch;
      stage16(Ah + ga, tAh + lo);
      stage16(Bh + gb, tBh + lo);
    }
    __syncthreads();
    bf16x8 ah[4], bh[4];
    #pragma unroll
    for (int i = 0; i < 4; i++){
      const int ao = (wr*64 + i*16 + lm)*32 + quad*8;
      const int bo = (wc*64 + i*16 + lm)*32 + quad*8;
      ah[i] = *(const bf16x8*)&tAh[ao];
      bh[i] = *(const bf16x8*)&tBh[bo];
    }
    #pragma unroll
    for (int i = 0; i < 4; i++)
      #pragma unroll
      for (int j = 0; j < 4; j++)
        acc[i][j] = __builtin_amdgcn_mfma_f32_16x16x32_bf16(ah[i], bh[j], acc[i][j], 0, 0, 0);
    __syncthreads();
  }

  float* Xr = shf;
  float* Xc = shf + 128*33;
  const int lrow = t >> 1, lh = t & 1;
  for (int e = 0; e < nepi; e++){
    const float* xr = e ? e1xr : e0xr;
    const float* xc = e ? e1xc : e0xc;
    const float* nr = e ? e1nr : e0nr;
    const float* nc = e ? e1nc : e0nc;
    const int slot = e ? s1 : s0;
    const int rslot = e ? rs1 : rs0;
    {
      const float* pr = xr + (size_t)(r0 + lrow) * DD + lh * 16;
      const float* pc = xc + (size_t)(c0 + lrow) * DD + lh * 16;
      float* dr = &Xr[lrow * 33 + lh * 16];
      float* dc = &Xc[lrow * 33 + lh * 16];
      #pragma unroll
      for (int u = 0; u < 4; u++){
        float4 a = ((const float4*)pr)[u];
        dr[4*u+0]=a.x; dr[4*u+1]=a.y; dr[4*u+2]=a.z; dr[4*u+3]=a.w;
        float4 b = ((const float4*)pc)[u];
        dc[4*u+0]=b.x; dc[4*u+1]=b.y; dc[4*u+2]=b.z; dc[4*u+3]=b.w;
      }
    }
    __syncthreads();
    float s = 0.f, s2 = 0.f;
    #pragma unroll 1
    for (int i = 0; i < 4; i++){
      #pragma unroll 1
      for (int rg = 0; rg < 4; rg++){
        const int rl = wr*64 + i*16 + quad*4 + rg;
        const float* xi = &Xr[rl*33];
        const float ni = nr[r0 + rl];
        #pragma unroll 1
        for (int j = 0; j < 4; j++){
          const int cl = wc*64 + j*16 + lm;
          const float* xj = &Xc[cl*33];
          float d = 0.f;
          #pragma unroll
          for (int k = 0; k < 32; k++) d = fmaf(xi[k], xj[k], d);
          const float Lval = __expf(-(ni + nc[c0 + cl] - 2.f*d) * (1.f/32.f));
          s += acc[i][j][rg] * Lval;
          if (doRed){
            const size_t o = (size_t)(r0 + rl) * NN + c0 + cl;
            s2 += bf2f(Ah[o]) * Lval;
          }
        }
      }
    }
    block_atomic_add(s * wgt, red, slots + slot);
    if (doRed) block_atomic_add(s2 * wgt, red, slots + rslot);
    __syncthreads();
  }
}

// ---------------- V = B * Kpq, Kpq generated on the fly (bf16, conflict-free) ----------
__global__ __launch_bounds__(256) void k_mfma_vgen(
    const ushort* __restrict__ BhM,
    const float* __restrict__ zq, const float* __restrict__ nq,
    const float* __restrict__ zp, const float* __restrict__ npp,
    ushort* __restrict__ Vh){
  __shared__ __align__(16) float Q[128*33];
  __shared__ __align__(16) float P[32*33];
  __shared__ float nqs[128];
  __shared__ float nps[32];
  __shared__ __align__(16) ushort tAh[4096];
  __shared__ __align__(16) ushort tBh[4096];
  const int r0 = blockIdx.y * 128, c0 = blockIdx.x * 128;
  const int t = threadIdx.x;
  const int L = t & 63, w = t >> 6;
  const int wr = w >> 1, wc = w & 1;
  const int lm = L & 15, quad = L >> 4;
  const int sch = (t & 3) * 8;
  {
    const float* pr = zq + (size_t)(c0 + (t>>1)) * DD + (t&1) * 16;
    float* dr = &Q[(t>>1)*33 + (t&1)*16];
    #pragma unroll
    for (int u = 0; u < 4; u++){
      float4 a = ((const float4*)pr)[u];
      dr[4*u+0]=a.x; dr[4*u+1]=a.y; dr[4*u+2]=a.z; dr[4*u+3]=a.w;
    }
  }
  if (t < 128) nqs[t] = nq[c0 + t];
  const int gl = t & 31, gg0 = t >> 5;
  f32x4 acc[4][4];
  #pragma unroll
  for (int i = 0; i < 4; i++)
    #pragma unroll
    for (int j = 0; j < 4; j++) acc[i][j] = (f32x4){0.f, 0.f, 0.f, 0.f};

  for (int ks = 0; ks < NN; ks += 32){
    {
      const int prr = t >> 3, pcc = (t & 7) * 4;
      *(float4*)&P[prr*33 + pcc] = *(const float4*)(zp + (size_t)(ks + prr) * DD + pcc);
    }
    if (t < 32) nps[t] = npp[ks + t];
    #pragma unroll
    for (int p = 0; p < 2; p++){
      const int row = p*64 + (t >> 2);
      const size_t ga = (size_t)(r0 + row) * NN + ks + sch;
      const int lo = row*32 + sch;
      stage16(BhM + ga, tAh + lo);
    }
    __syncthreads();
    {
      const float* pv = &P[gl*33];
      const float npl = nps[gl];
      #pragma unroll 1
      for (int m = 0; m < 16; m++){
        const int gn = gg0 + 8*m;
        const float* qv = &Q[gn*33];
        float d = 0.f;
        #pragma unroll
        for (int k = 0; k < 32; k++) d = fmaf(qv[k], pv[k], d);
        tBh[gn*32 + gl] = f2bf(__expf(-(nqs[gn] + npl - 2.f*d) * (1.f/32.f)));
      }
    }
    __syncthreads();
    bf16x8 ah[4], bh[4];
    #pragma unroll
    for (int i = 0; i < 4; i++){
      const int ao = (wr*64 + i*16 + lm)*32 + quad*8;
      const int bo = (wc*64 + i*16 + lm)*32 + quad*8;
      ah[i] = *(const bf16x8*)&tAh[ao];
      bh[i] = *(const bf16x8*)&tBh[bo];
    }
    #pragma unroll
    for (int i = 0; i < 4; i++)
      #pragma unroll
      for (int j = 0; j < 4; j++)
        acc[i][j] = __builtin_amdgcn_mfma_f32_16x16x32_bf16(ah[i], bh[j], acc[i][j], 0, 0, 0);
    __syncthreads();
  }
  #pragma unroll
  for (int i = 0; i < 4; i++)
    #pragma unroll
    for (int j = 0; j < 4; j++)
      #pragma unroll
      for (int rg = 0; rg < 4; rg++){
        const int row = wr*64 + i*16 + quad*4 + rg;
        const int col = wc*64 + j*16 + lm;
        Vh[(size_t)(r0 + row) * NN + c0 + col] = f2bf(acc[i][j][rg]);
      }
}

// ---------------- blocked Gauss-Jordan: 512-thread diag block inverse (NB=128) ---------
__global__ __launch_bounds__(512) void k_gj_diag(float* __restrict__ M0, float* __restrict__ M1,
                                                 float* __restrict__ Pbuf,
                                                 ushort* __restrict__ Pth, ushort* __restrict__ Ptl,
                                                 int kb){
  float* M = blockIdx.x ? M1 : M0;
  float* P = Pbuf + (size_t)blockIdx.x * NB * NB;
  ushort* Ph = Pth + (size_t)blockIdx.x * NB * NB;
  ushort* Pl = Ptl + (size_t)blockIdx.x * NB * NB;
  __shared__ float rowbuf[NB];
  __shared__ float colbuf[NB];
  const int t = threadIdx.x;
  const int r = t >> 2, g = t & 3;
  const int k0 = kb * NB;
  float reg[32];
  #pragma unroll
  for (int j = 0; j < 32; j++) reg[j] = M[(size_t)(k0 + r) * NN + k0 + g + 4*j];
  __syncthreads();
  #pragma unroll 1
  for (int jj = 0; jj < NB; jj++){
    if (r == jj){
      #pragma unroll
      for (int j = 0; j < 32; j++) rowbuf[g + 4*j] = reg[j];
    }
    if (g == (jj & 3)) colbuf[r] = reg[jj >> 2];
    __syncthreads();
    const float p = 1.0f / rowbuf[jj];
    if (r == jj){
      #pragma unroll
      for (int j = 0; j < 32; j++){
        const int c = g + 4*j;
        reg[j] = (c == jj) ? p : reg[j] * p;
      }
    } else {
      const float f = colbuf[r] * p;
      #pragma unroll
      for (int j = 0; j < 32; j++){
        const int c = g + 4*j;
        reg[j] = (c == jj) ? (-f) : fmaf(-f, rowbuf[c], reg[j]);
      }
    }
    __syncthreads();
  }
  #pragma unroll
  for (int j = 0; j < 32; j++){
    const int c = g + 4*j;
    P[r * NB + c] = reg[j];
    ushort h = f2bf(reg[j]);
    Ph[(size_t)c * NB + r] = h;                 // transposed split
    Pl[(size_t)c * NB + r] = f2bf(reg[j] - bf2f(h));
  }
}

// Panel: T = P @ M[krow, :]; writes T^T split + C (col-panel) split
__global__ __launch_bounds__(256) void k_gj_panel(float* __restrict__ M0, float* __restrict__ M1,
                                                  const float* __restrict__ Pbuf,
                                                  ushort* __restrict__ Tth, ushort* __restrict__ Ttl,
                                                  ushort* __restrict__ Chh, ushort* __restrict__ Chl,
                                                  int kb){
  const int mat = blockIdx.y;
  float* M = mat ? M1 : M0;
  const float* P = Pbuf + (size_t)mat * NB * NB;
  ushort* Th = Tth + (size_t)mat * NN * NB;
  ushort* Tl = Ttl + (size_t)mat * NN * NB;
  ushort* Ch = Chh + (size_t)mat * NN * NB;
  ushort* Cl = Chl + (size_t)mat * NN * NB;
  const int jb = blockIdx.x;
  const int k0 = kb * NB, j0 = jb * NB;
  const int t = threadIdx.x;
  { // C split copy of M[:, kcol] panel (rows j0..j0+127)
    const int row = t >> 1, half = (t & 1) * 64;
    const float* src = M + (size_t)(j0 + row) * NN + k0 + half;
    ushort* dh = Ch + (size_t)(j0 + row) * NB + half;
    ushort* dl = Cl + (size_t)(j0 + row) * NB + half;
    #pragma unroll
    for (int u = 0; u < 16; u++){
      float4 v = ((const float4*)src)[u];
      ushort h0 = f2bf(v.x), h1 = f2bf(v.y), h2 = f2bf(v.z), h3 = f2bf(v.w);
      ((ushort4*)dh)[u] = make_ushort4(h0, h1, h2, h3);
      ((ushort4*)dl)[u] = make_ushort4(f2bf(v.x - bf2f(h0)), f2bf(v.y - bf2f(h1)),
                                       f2bf(v.z - bf2f(h2)), f2bf(v.w - bf2f(h3)));
    }
  }
  __shared__ float As[128 * 17];
  __shared__ float Bs[16 * 132];
  const int tx = t & 15, ty = t >> 4;
  const int lrow = t >> 1, lh = t & 1;
  float acc[8][8];
  #pragma unroll
  for (int u = 0; u < 8; u++)
    #pragma unroll
    for (int v = 0; v < 8; v++) acc[u][v] = 0.f;
  for (int ks = 0; ks < NB; ks += 16){
    {
      const float* pa = P + (size_t)lrow * NB + ks + lh * 8;
      float4 a0 = ((const float4*)pa)[0];
      float4 a1 = ((const float4*)pa)[1];
      float* da = &As[lrow * 17 + lh * 8];
      da[0]=a0.x; da[1]=a0.y; da[2]=a0.z; da[3]=a0.w;
      da[4]=a1.x; da[5]=a1.y; da[6]=a1.z; da[7]=a1.w;
      const int kkl = t >> 4, c8 = (t & 15) * 8;
      const float* pb = M + (size_t)(k0 + ks + kkl) * NN + j0 + c8;
      float4 b0 = ((const float4*)pb)[0];
      float4 b1 = ((const float4*)pb)[1];
      *(float4*)&Bs[kkl*132 + c8]     = b0;
      *(float4*)&Bs[kkl*132 + c8 + 4] = b1;
    }
    __syncthreads();
    #pragma unroll
    for (int kk = 0; kk < 16; kk++){
      float a[8], b[8];
      #pragma unroll
      for (int u = 0; u < 8; u++) a[u] = As[RMAP(ty,u)*17 + kk];
      float4 b0 = *(const float4*)&Bs[kk*132 + tx*4];
      float4 b1 = *(const float4*)&Bs[kk*132 + tx*4 + 64];
      b[0]=b0.x; b[1]=b0.y; b[2]=b0.z; b[3]=b0.w;
      b[4]=b1.x; b[5]=b1.y; b[6]=b1.z; b[7]=b1.w;
      #pragma unroll
      for (int u = 0; u < 8; u++)
        #pragma unroll
        for (int v = 0; v < 8; v++) acc[u][v] += a[u] * b[v];
    }
    __syncthreads();
  }
  // write T transposed, split
  #pragma unroll
  for (int u = 0; u < 8; u++){
    const int rr = RMAP(ty,u);
    #pragma unroll
    for (int v = 0; v < 8; v++){
      const int cc = j0 + CMAP(tx,v);
      float val = acc[u][v];
      ushort h = f2bf(val);
      Th[(size_t)cc * NB + rr] = h;
      Tl[(size_t)cc * NB + rr] = f2bf(val - bf2f(h));
    }
  }
}

// Trailing update (MFMA split-3) + k-row writeback
__global__ __launch_bounds__(256) void k_gj_update(float* __restrict__ M0, float* __restrict__ M1,
    const float* __restrict__ Pbuf,
    const ushort* __restrict__ Pth, const ushort* __restrict__ Ptl,
    const ushort* __restrict__ Tth, const ushort* __restrict__ Ttl,
    const ushort* __restrict__ Chh, const ushort* __restrict__ Chl, int kb){
  __shared__ __align__(16) ushort tAh[4096];
  __shared__ __align__(16) ushort tAl[4096];
  __shared__ __align__(16) ushort tBh[4096];
  __shared__ __align__(16) ushort tBl[4096];
  const int mat = blockIdx.z;
  float* M = mat ? M1 : M0;
  const float* P = Pbuf + (size_t)mat * NB * NB;
  const ushort* Ph = Pth + (size_t)mat * NB * NB;
  const ushort* Pl = Ptl + (size_t)mat * NB * NB;
  const ushort* Th = Tth + (size_t)mat * NN * NB;
  const ushort* Tl = Ttl + (size_t)mat * NN * NB;
  const ushort* Ch = Chh + (size_t)mat * NN * NB;
  const ushort* Cl = Chl + (size_t)mat * NN * NB;
  const int jb = blockIdx.x, ib = blockIdx.y;
  const int k0 = kb * NB, i0 = ib * NB, j0 = jb * NB;
  const int t = threadIdx.x;
  if (ib == kb){
    if (jb == kb){
      const int row = t >> 1, half = (t & 1) * 64;
      float* dst = M + (size_t)(k0 + row) * NN + j0 + half;
      const float* src = P + (size_t)row * NB + half;
      #pragma unroll
      for (int u = 0; u < 16; u++) ((float4*)dst)[u] = ((const float4*)src)[u];
    } else {
      const int n = t & 127, rh = (t >> 7) * 64;
      #pragma unroll 1
      for (int m = 0; m < 64; m++){
        const int r = rh + m;
        const size_t o = (size_t)(j0 + n) * NB + r;
        M[(size_t)(k0 + r) * NN + j0 + n] = bf2f(Th[o]) + bf2f(Tl[o]);
      }
    }
    return;
  }
  const int L = t & 63, w = t >> 6;
  const int wr = w >> 1, wc = w & 1;
  const int lm = L & 15, quad = L >> 4;
  const int sch = (t & 3) * 8;
  const ushort* Bh = (jb == kb) ? Ph : (Th + (size_t)j0 * NB);
  const ushort* Bl = (jb == kb) ? Pl : (Tl + (size_t)j0 * NB);
  const ushort* Ahp = Ch + (size_t)i0 * NB;
  const ushort* Alp = Cl + (size_t)i0 * NB;
  f32x4 acc[4][4];
  #pragma unroll
  for (int i = 0; i < 4; i++)
    #pragma unroll
    for (int j = 0; j < 4; j++) acc[i][j] = (f32x4){0.f, 0.f, 0.f, 0.f};
  for (int ks = 0; ks < NB; ks += 32){
    #pragma unroll
    for (int p = 0; p < 2; p++){
      const int row = p*64 + (t >> 2);
      const size_t ga = (size_t)row * NB + ks + sch;
      const int lo = row*32 + sch;
      stage16(Ahp + ga, tAh + lo);
      stage16(Alp + ga, tAl + lo);
      stage16(Bh + ga, tBh + lo);
      stage16(Bl + ga, tBl + lo);
    }
    __syncthreads();
    bf16x8 ah[4], al[4], bh[4], bl[4];
    #pragma unroll
    for (int i = 0; i < 4; i++){
      const int ao = (wr*64 + i*16 + lm)*32 + quad*8;
      const int bo = (wc*64 + i*16 + lm)*32 + quad*8;
      ah[i] = *(const bf16x8*)&tAh[ao];
      al[i] = *(const bf16x8*)&tAl[ao];
      bh[i] = *(const bf16x8*)&tBh[bo];
      bl[i] = *(const bf16x8*)&tBl[bo];
    }
    #pragma unroll
    for (int i = 0; i < 4; i++)
      #pragma unroll
      for (int j = 0; j < 4; j++){
        acc[i][j] = __builtin_amdgcn_mfma_f32_16x16x32_bf16(ah[i], bh[j], acc[i][j], 0, 0, 0);
        acc[i][j] = __builtin_amdgcn_mfma_f32_16x16x32_bf16(ah[i], bl[j], acc[i][j], 0, 0, 0);
        acc[i][j] = __builtin_amdgcn_mfma_f32_16x16x32_bf16(al[i], bh[j], acc[i][j], 0, 0, 0);
      }
    __syncthreads();
  }
  if (jb == kb){
    #pragma unroll
    for (int i = 0; i < 4; i++)
      #pragma unroll
      for (int j = 0; j < 4; j++)
        #pragma unroll
        for (int rg = 0; rg < 4; rg++){
          const int row = wr*64 + i*16 + quad*4 + rg;
          const int col = wc*64 + j*16 + lm;
          M[(size_t)(i0 + row) * NN + k0 + col] = -acc[i][j][rg];
        }
  } else {
    #pragma unroll
    for (int i = 0; i < 4; i++)
      #pragma unroll
      for (int j = 0; j < 4; j++)
        #pragma unroll
        for (int rg = 0; rg < 4; rg++){
          const int row = wr*64 + i*16 + quad*4 + rg;
          const int col = wc*64 + j*16 + lm;
          float* pm = M + (size_t)(i0 + row) * NN + j0 + col;
          *pm = *pm - acc[i][j][rg];
        }
  }
}

// ---------------- final combine ----------------
__global__ void k_combine(const float* __restrict__ slots, float* __restrict__ out){
  if (threadIdx.x == 0 && blockIdx.x == 0){
    const double invN2 = 1.0 / ((double)NN * (double)NN);
    double term1 = ((double)slots[0] + (double)slots[1] - 2.0 * (double)slots[2]) * invN2;
    double pairs = 0.0;
    for (int p = 0; p < 3; p++){
      const float* s = slots + 4 + 5 * p;
      pairs += ((double)s[0] - 0.2 * (double)s[1] + (double)s[2] - 0.2 * (double)s[3] - 2.0 * (double)s[4]);
    }
    out[0] = (float)(1.0 * term1 + 500.0 * pairs * invN2);
    out[1] = (float)((double)slots[3] / (2.0 * (double)NN));
  }
}

// ---------------- host ----------------
extern "C" void kernel_launch(void* const* d_in, const int* in_sizes, int n_in,
                              void* d_out, int out_size, void* d_ws, size_t ws_size,
                              hipStream_t stream){
  const float* x    = (const float*)d_in[0];
  const float* z    = (const float*)d_in[1];
  const float* zz   = (const float*)d_in[2];
  const float* xx   = (const float*)d_in[3];
  const float* stdn = (const float*)d_in[4];
  float* out = (float*)d_out;
  float* ws  = (float*)d_ws;

  const size_t NN2 = (size_t)NN * NN;
  float* R0 = ws;
  float* R1 = R0 + NN2;
  float* R2 = R1 + NN2;
  float* PanelF = R2 + NN2;
  ushort* Tth = (ushort*)PanelF;
  ushort* Ttl = Tth + 2 * (size_t)NB * NN;
  ushort* Chh = Ttl + 2 * (size_t)NB * NN;
  ushort* Chl = Chh + 2 * (size_t)NB * NN;
  float* Pb   = PanelF + 4 * (size_t)NB * NN;   // fp32 P (2 mats)
  ushort* Pth = (ushort*)(Pb + 2 * (size_t)NB * NB);
  ushort* Ptl = Pth + 2 * (size_t)NB * NB;
  float* slots= (float*)(Ptl + 2 * (size_t)NB * NB);
  float* stdsq= slots + 32;
  float* zrs  = stdsq + NN;
  float* nzz  = zrs + (size_t)NN * NV;
  float* nz8  = nzz + (size_t)NV * NN;
  float* nrmz = nz8 + (size_t)NV * NN;

  ushort* R0h = (ushort*)R0;   // B hi (bf16)
  ushort* R2h = (ushort*)R2;   // A hi (bf16)
  ushort* Vh  = (ushort*)R1;   // V hi (bf16)

  dim3 g32(NBLK, NBLK);

  k_zero<<<1, 64, 0, stream>>>(slots, 32);
  k_norms<<<(NN * NV) / 256, 256, 0, stream>>>(z, zz, stdn, stdsq, zrs, nzz, nz8);
  k_rownorm<<<NN / 256, 256, 0, stream>>>(nz8, nrmz);
  k_nll<<<1024, 256, 0, stream>>>(x, xx, slots);
  k_sqq<<<NTRI, 256, 0, stream>>>(z, nrmz, slots);
  k_spp_sqp<<<g32, 256, 0, stream>>>(stdn, stdsq, zrs, nrmz, slots);

  const float* zz0 = zz;            const float* z0 = z;
  const float* zz1 = zz + VD;       const float* z1 = z + VD;
  const float* nzz0 = nzz;          const float* nz0 = nz8;
  const float* nzz1 = nzz + NN;     const float* nz1 = nz8 + NN;

  for (int b = 1; b <= 2; b++){
    const float* zzb = zz + b*VD;  const float* nzzb = nzz + (size_t)b*NN;
    const float* zb  = z + b*VD;   const float* nzb  = nz8 + (size_t)b*NN;
    k_rbf<<<g32, 256, 0, stream>>>(zzb, zzb, nzzb, nzzb, 0.2f, R0);
    k_rbf<<<g32, 256, 0, stream>>>(zb,  zb,  nzb,  nzb,  0.2f, R1);
    for (int kb = 0; kb < NBLK; kb++){
      k_gj_diag<<<2, 512, 0, stream>>>(R0, R1, Pb, Pth, Ptl, kb);
      k_gj_panel<<<dim3(NBLK, 2), 256, 0, stream>>>(R0, R1, Pb, Tth, Ttl, Chh, Chl, kb);
      k_gj_update<<<dim3(NBLK, NBLK, 2), 256, 0, stream>>>(R0, R1, Pb, Pth, Ptl,
                                                           Tth, Ttl, Chh, Chl, kb);
    }
    // bf16 casts: A -> R2h, B -> R0h
    k_split<<<16384, 256, 0, stream>>>(R0, R2h);
    k_split<<<16384, 256, 0, stream>>>(R1, R0h);
    // V = B * Kpq (on-the-fly bf16 Kpq); dest R1
    k_mfma_vgen<<<g32, 256, 0, stream>>>(R0h, zzb, nzzb, zb, nzb, Vh);
    // trace GEMMs (pure bf16) with fused tr(L*A) reduction
    if (b == 1){
      k_mfma_tr<<<NTRI, 256, 0, stream>>>(R2h, R2h, 1, 1, 1,
                                          zz0, zz0, nzz0, nzz0, 5, 4,
                                          nullptr, nullptr, nullptr, nullptr, 0, 0, slots);
      k_mfma_tr<<<NTRI, 256, 0, stream>>>(R0h, R0h, 1, 1, 1,
                                          z0, z0, nz0, nz0, 7, 6,
                                          nullptr, nullptr, nullptr, nullptr, 0, 0, slots);
      k_mfma_tr<<<g32, 256, 0, stream>>>(R2h, Vh, 0, 0, 1,
                                         zz0, z0, nzz0, nz0, 8, 0,
                                         nullptr, nullptr, nullptr, nullptr, 0, 0, slots);
    } else {
      k_mfma_tr<<<NTRI, 256, 0, stream>>>(R2h, R2h, 1, 1, 2,
                                          zz1, zz1, nzz1, nzz1, 10, 9,
                                          zz0, zz0, nzz0, nzz0, 15, 14, slots);
      k_mfma_tr<<<NTRI, 256, 0, stream>>>(R0h, R0h, 1, 1, 2,
                                          z1, z1, nz1, nz1, 12, 11,
                                          z0, z0, nz0, nz0, 17, 16, slots);
      k_mfma_tr<<<g32, 256, 0, stream>>>(R2h, Vh, 0, 0, 2,
                                         zz1, z1, nzz1, nz1, 13, 0,
                                         zz0, z0, nzz0, nz0, 18, 0, slots);
    }
  }
  k_combine<<<1, 1, 0, stream>>>(slots, out);
}

// Round 10
// 31591.989 us; speedup vs baseline: 1.0876x; 1.0876x over previous
//
#include <hip/hip_runtime.h>
#include <math.h>

// Problem constants (fixed by setup_inputs)
#define NN 4096      // N samples
#define DD 256       // flat endo dim (8 vars * 32)
#define NV 8         // vars
#define VD 32        // per-var dim
#define NB 128       // GJ block size (reg[32]/512-thread diag is the proven config)
#define NBLK (NN/NB) // 32
#define NTRI (NBLK*(NBLK+1)/2)  // 528

// fp32-GEMM output ownership mapping (bank-conflict-free)
#define RMAP(ty,u) ((ty)*4 + (((u)>>2)<<6) + ((u)&3))
#define CMAP(tx,v) ((tx)*4 + (((v)>>2)<<6) + ((v)&3))

typedef __attribute__((ext_vector_type(8))) short bf16x8;
typedef __attribute__((ext_vector_type(4))) float f32x4;

#define AS1(p) ((const __attribute__((address_space(1))) void*)(p))
#define AS3(p) ((__attribute__((address_space(3))) void*)(p))

__device__ __forceinline__ void stage16(const ushort* g, ushort* l){
  __builtin_amdgcn_global_load_lds(AS1(g), AS3(l), 16, 0, 0);
}

__device__ __forceinline__ ushort f2bf(float x){
  uint u = __float_as_uint(x);
  u += 0x7FFFu + ((u >> 16) & 1u);
  return (ushort)(u >> 16);
}
__device__ __forceinline__ float bf2f(ushort h){ return __uint_as_float(((uint)h) << 16); }

// triangular block map: p -> (bi >= bj)
__device__ __forceinline__ void tri_map(int p, int& bi, int& bj){
  int b = (int)((sqrtf(8.0f * (float)p + 1.0f) - 1.0f) * 0.5f);
  while ((b + 1) * (b + 2) / 2 <= p) b++;
  while (b * (b + 1) / 2 > p) b--;
  bi = b; bj = p - b * (b + 1) / 2;
}

// ---------------- helpers ----------------
__device__ __forceinline__ void block_atomic_add(float v, float* red, float* dst){
  #pragma unroll
  for (int off = 32; off > 0; off >>= 1) v += __shfl_down(v, off, 64);
  const int lane = threadIdx.x & 63;
  const int w = threadIdx.x >> 6;
  if (lane == 0) red[w] = v;
  __syncthreads();
  if (threadIdx.x == 0) atomicAdd(dst, red[0] + red[1] + red[2] + red[3]);
  __syncthreads();
}

// ---------------- small utility kernels ----------------
__global__ void k_zero(float* p, int n){
  int i = blockIdx.x * blockDim.x + threadIdx.x;
  if (i < n) p[i] = 0.f;
}

__global__ void k_norms(const float* __restrict__ z, const float* __restrict__ zz,
                        const float* __restrict__ stdn,
                        float* __restrict__ stdsq, float* __restrict__ zrs,
                        float* __restrict__ nzz, float* __restrict__ nz8){
  int t = blockIdx.x * blockDim.x + threadIdx.x;
  if (t >= NN * NV) return;
  int i = t / NV, v = t % NV;
  const float* zp  = z  + (size_t)i * DD + v * VD;
  const float* zzp = zz + (size_t)i * DD + v * VD;
  float s1 = 0.f, s2 = 0.f, s2z = 0.f;
  #pragma unroll
  for (int k = 0; k < VD; k++){
    float a = zp[k];  s1 += a; s2 += a * a;
    float b = zzp[k]; s2z += b * b;
  }
  zrs[(size_t)i * NV + v] = s1;
  nz8[(size_t)v * NN + i] = s2;
  nzz[(size_t)v * NN + i] = s2z;
  if (v == 0){
    float s = 0.f;
    #pragma unroll
    for (int u = 0; u < NV; u++){ float a = stdn[(size_t)i * NV + u]; s += a * a; }
    stdsq[i] = s;
  }
}

__global__ void k_rownorm(const float* __restrict__ nz8, float* __restrict__ nrmz){
  int i = blockIdx.x * blockDim.x + threadIdx.x;
  if (i < NN){
    float s = 0.f;
    #pragma unroll
    for (int v = 0; v < NV; v++) s += nz8[(size_t)v * NN + i];
    nrmz[i] = s;
  }
}

__global__ __launch_bounds__(256) void k_nll(const float* __restrict__ x,
                                             const float* __restrict__ xx,
                                             float* __restrict__ slots){
  __shared__ float red[4];
  float s = 0.f;
  const int total = NN * DD;
  for (int i = (blockIdx.x * 256 + threadIdx.x) * 4; i < total; i += gridDim.x * 256 * 4){
    float4 a = *(const float4*)(x + i);
    float4 b = *(const float4*)(xx + i);
    float d0 = b.x - a.x, d1 = b.y - a.y, d2 = b.z - a.z, d3 = b.w - a.w;
    s += d0*d0 + d1*d1 + d2*d2 + d3*d3;
  }
  block_atomic_add(s, red, slots + 3);
}

// ---------------- first (exo-free) MMD term ----------------
__global__ __launch_bounds__(256) void k_sqq(const float* __restrict__ z,
                                             const float* __restrict__ nrm,
                                             float* __restrict__ slots){
  __shared__ float Xr[128 * 33];
  __shared__ float Xc[128 * 33];
  __shared__ float red[4];
  int bi, bj; tri_map(blockIdx.x, bi, bj);
  const int r0 = bi * 128, c0 = bj * 128;
  const float wgt = (bi != bj) ? 2.f : 1.f;
  const int t = threadIdx.x;
  const int tx = t & 15, ty = t >> 4;
  const int lrow = t >> 1, lh = t & 1;
  float acc[8][8];
  #pragma unroll
  for (int u = 0; u < 8; u++)
    #pragma unroll
    for (int v = 0; v < 8; v++) acc[u][v] = 0.f;
  for (int ks = 0; ks < DD; ks += 32){
    const float* pr = z + (size_t)(r0 + lrow) * DD + ks + lh * 16;
    const float* pc = z + (size_t)(c0 + lrow) * DD + ks + lh * 16;
    float* dr = &Xr[lrow * 33 + lh * 16];
    float* dc = &Xc[lrow * 33 + lh * 16];
    #pragma unroll
    for (int u = 0; u < 4; u++){
      float4 a = ((const float4*)pr)[u];
      dr[4*u+0] = a.x; dr[4*u+1] = a.y; dr[4*u+2] = a.z; dr[4*u+3] = a.w;
      float4 b = ((const float4*)pc)[u];
      dc[4*u+0] = b.x; dc[4*u+1] = b.y; dc[4*u+2] = b.z; dc[4*u+3] = b.w;
    }
    __syncthreads();
    #pragma unroll
    for (int kk = 0; kk < 32; kk++){
      float a[8], b[8];
      #pragma unroll
      for (int u = 0; u < 8; u++) a[u] = Xr[RMAP(ty,u)*33 + kk];
      #pragma unroll
      for (int v = 0; v < 8; v++) b[v] = Xc[CMAP(tx,v)*33 + kk];
      #pragma unroll
      for (int u = 0; u < 8; u++)
        #pragma unroll
        for (int v = 0; v < 8; v++) acc[u][v] += a[u] * b[v];
    }
    __syncthreads();
  }
  float s = 0.f;
  #pragma unroll 1
  for (int u = 0; u < 8; u++){
    const float ni = nrm[r0 + RMAP(ty,u)];
    #pragma unroll 1
    for (int v = 0; v < 8; v++)
      s += __expf(-(ni + nrm[c0 + CMAP(tx,v)] - 2.f * acc[u][v]) * (1.f/2048.f));
  }
  block_atomic_add(s * wgt, red, slots + 0);
}

__global__ __launch_bounds__(256) void k_spp_sqp(const float* __restrict__ stdn,
                                                 const float* __restrict__ stdsq,
                                                 const float* __restrict__ zrs,
                                                 const float* __restrict__ nrmz,
                                                 float* __restrict__ slots){
  __shared__ float sI[128*9], sJ[128*9], zI[128*9];
  __shared__ float qI[128], qJ[128], nI[128];
  __shared__ float red[4];
  const int r0 = blockIdx.y * 128, c0 = blockIdx.x * 128;
  const int t = threadIdx.x;
  if (t < 128){
    #pragma unroll
    for (int v = 0; v < 8; v++){
      sI[t*9+v] = stdn[(size_t)(r0+t)*NV + v];
      sJ[t*9+v] = stdn[(size_t)(c0+t)*NV + v];
      zI[t*9+v] = zrs[(size_t)(r0+t)*NV + v];
    }
    qI[t] = stdsq[r0+t]; qJ[t] = stdsq[c0+t]; nI[t] = nrmz[r0+t];
  }
  __syncthreads();
  const int tx = t & 15, ty = t >> 4;
  float spp = 0.f, sqp = 0.f;
  #pragma unroll 1
  for (int u = 0; u < 8; u++){
    int i = ty + 16*u;
    #pragma unroll 1
    for (int v = 0; v < 8; v++){
      int j = tx + 16*v;
      float dpp = 0.f, dqp = 0.f;
      #pragma unroll
      for (int k = 0; k < 8; k++){
        float sj = sJ[j*9+k];
        dpp += sI[i*9+k] * sj;
        dqp += zI[i*9+k] * sj;
      }
      spp += __expf(-(qI[i] + qJ[j] - 2.f*dpp) * (1.f/64.f));
      sqp += __expf(-(nI[i] + 32.f*qJ[j] - 2.f*dqp) * (1.f/2048.f));
    }
  }
  block_atomic_add(spp, red, slots + 1);
  block_atomic_add(sqp, red, slots + 2);
}

// ---------------- RBF Gram matrix build (K=32) ----------------
__global__ __launch_bounds__(256) void k_rbf(const float* __restrict__ Xr_,
                                             const float* __restrict__ Xc_,
                                             const float* __restrict__ nr,
                                             const float* __restrict__ nc,
                                             float lam, float* __restrict__ M){
  __shared__ float Xr[128 * 33];
  __shared__ float Xc[128 * 33];
  const int r0 = blockIdx.y * 128, c0 = blockIdx.x * 128;
  const int t = threadIdx.x;
  const int tx = t & 15, ty = t >> 4;
  const int lrow = t >> 1, lh = t & 1;
  {
    const float* pr = Xr_ + (size_t)(r0 + lrow) * DD + lh * 16;
    const float* pc = Xc_ + (size_t)(c0 + lrow) * DD + lh * 16;
    float* dr = &Xr[lrow * 33 + lh * 16];
    float* dc = &Xc[lrow * 33 + lh * 16];
    #pragma unroll
    for (int u = 0; u < 4; u++){
      float4 a = ((const float4*)pr)[u];
      dr[4*u+0]=a.x; dr[4*u+1]=a.y; dr[4*u+2]=a.z; dr[4*u+3]=a.w;
      float4 b = ((const float4*)pc)[u];
      dc[4*u+0]=b.x; dc[4*u+1]=b.y; dc[4*u+2]=b.z; dc[4*u+3]=b.w;
    }
  }
  __syncthreads();
  #pragma unroll 1
  for (int u = 0; u < 8; u++){
    const int gi = r0 + RMAP(ty,u);
    const float* xi = &Xr[RMAP(ty,u)*33];
    const float ni = nr[gi];
    float vals[8];
    #pragma unroll 1
    for (int v = 0; v < 8; v++){
      const int gj = c0 + CMAP(tx,v);
      const float* xj = &Xc[CMAP(tx,v)*33];
      float d = 0.f;
      #pragma unroll
      for (int k = 0; k < 32; k++) d += xi[k] * xj[k];
      float e = __expf(-(ni + nc[gj] - 2.f*d) * (1.f/32.f));
      if (gi == gj) e += lam;
      vals[v] = e;
    }
    float* pd = M + (size_t)gi * NN + c0 + tx*4;
    *(float4*)pd        = make_float4(vals[0], vals[1], vals[2], vals[3]);
    *(float4*)(pd + 64) = make_float4(vals[4], vals[5], vals[6], vals[7]);
  }
}

// ---------------- fp32 -> bf16 (hi only; trace GEMMs run pure bf16) ----------------
__global__ __launch_bounds__(256) void k_split(const float* __restrict__ S,
                                               ushort* __restrict__ H){
  size_t i = ((size_t)blockIdx.x * 256 + threadIdx.x) * 4;
  float4 x = *(const float4*)(S + i);
  *(ushort4*)(H + i) = make_ushort4(f2bf(x.x), f2bf(x.y), f2bf(x.z), f2bf(x.w));
}

// ---------------- MFMA bf16 GEMM + fused RBF-trace epilogue(s) + fused tr(L*A) ----
__global__ __launch_bounds__(256) void k_mfma_tr(
    const ushort* __restrict__ Ah, const ushort* __restrict__ Bh,
    int sym, int doRed, int nepi,
    const float* e0xr, const float* e0xc, const float* e0nr, const float* e0nc, int s0, int rs0,
    const float* e1xr, const float* e1xc, const float* e1nr, const float* e1nc, int s1, int rs1,
    float* __restrict__ slots){
  __shared__ __align__(16) float shf[2*128*33 + 4];
  ushort* tAh = (ushort*)shf;
  ushort* tBh = tAh + 4096;
  float* red = shf + 2*128*33;
  int bi, bj;
  if (sym){ tri_map(blockIdx.x, bi, bj); } else { bi = blockIdx.y; bj = blockIdx.x; }
  const int r0 = bi * 128, c0 = bj * 128;
  const float wgt = (sym && bi != bj) ? 2.f : 1.f;
  const int t = threadIdx.x;
  const int L = t & 63, w = t >> 6;
  const int wr = w >> 1, wc = w & 1;
  const int lm = L & 15, quad = L >> 4;
  const int sch = (t & 3) * 8;

  f32x4 acc[4][4];
  #pragma unroll
  for (int i = 0; i < 4; i++)
    #pragma unroll
    for (int j = 0; j < 4; j++) acc[i][j] = (f32x4){0.f, 0.f, 0.f, 0.f};

  for (int ks = 0; ks < NN; ks += 32){
    #pragma unroll
    for (int p = 0; p < 2; p++){
      const int row = p*64 + (t >> 2);
      const size_t ga = (size_t)(r0 + row) * NN + ks + sch;
      const size_t gb = (size_t)(c0 + row) * NN + ks + sch;
      const int lo = row*32 + sch;
      stage16(Ah + ga, tAh + lo);
      stage16(Bh + gb, tBh + lo);
    }
    __syncthreads();
    bf16x8 ah[4], bh[4];
    #pragma unroll
    for (int i = 0; i < 4; i++){
      const int ao = (wr*64 + i*16 + lm)*32 + quad*8;
      const int bo = (wc*64 + i*16 + lm)*32 + quad*8;
      ah[i] = *(const bf16x8*)&tAh[ao];
      bh[i] = *(const bf16x8*)&tBh[bo];
    }
    #pragma unroll
    for (int i = 0; i < 4; i++)
      #pragma unroll
      for (int j = 0; j < 4; j++)
        acc[i][j] = __builtin_amdgcn_mfma_f32_16x16x32_bf16(ah[i], bh[j], acc[i][j], 0, 0, 0);
    __syncthreads();
  }

  float* Xr = shf;
  float* Xc = shf + 128*33;
  const int lrow = t >> 1, lh = t & 1;
  for (int e = 0; e < nepi; e++){
    const float* xr = e ? e1xr : e0xr;
    const float* xc = e ? e1xc : e0xc;
    const float* nr = e ? e1nr : e0nr;
    const float* nc = e ? e1nc : e0nc;
    const int slot = e ? s1 : s0;
    const int rslot = e ? rs1 : rs0;
    {
      const float* pr = xr + (size_t)(r0 + lrow) * DD + lh * 16;
      const float* pc = xc + (size_t)(c0 + lrow) * DD + lh * 16;
      float* dr = &Xr[lrow * 33 + lh * 16];
      float* dc = &Xc[lrow * 33 + lh * 16];
      #pragma unroll
      for (int u = 0; u < 4; u++){
        float4 a = ((const float4*)pr)[u];
        dr[4*u+0]=a.x; dr[4*u+1]=a.y; dr[4*u+2]=a.z; dr[4*u+3]=a.w;
        float4 b = ((const float4*)pc)[u];
        dc[4*u+0]=b.x; dc[4*u+1]=b.y; dc[4*u+2]=b.z; dc[4*u+3]=b.w;
      }
    }
    __syncthreads();
    float s = 0.f, s2 = 0.f;
    #pragma unroll 1
    for (int i = 0; i < 4; i++){
      #pragma unroll 1
      for (int rg = 0; rg < 4; rg++){
        const int rl = wr*64 + i*16 + quad*4 + rg;
        const float* xi = &Xr[rl*33];
        const float ni = nr[r0 + rl];
        #pragma unroll 1
        for (int j = 0; j < 4; j++){
          const int cl = wc*64 + j*16 + lm;
          const float* xj = &Xc[cl*33];
          float d = 0.f;
          #pragma unroll
          for (int k = 0; k < 32; k++) d = fmaf(xi[k], xj[k], d);
          const float Lval = __expf(-(ni + nc[c0 + cl] - 2.f*d) * (1.f/32.f));
          s += acc[i][j][rg] * Lval;
          if (doRed){
            const size_t o = (size_t)(r0 + rl) * NN + c0 + cl;
            s2 += bf2f(Ah[o]) * Lval;
          }
        }
      }
    }
    block_atomic_add(s * wgt, red, slots + slot);
    if (doRed) block_atomic_add(s2 * wgt, red, slots + rslot);
    __syncthreads();
  }
}

// ---------------- V = B * Kpq, Kpq generated on the fly (bf16, conflict-free) ----------
__global__ __launch_bounds__(256) void k_mfma_vgen(
    const ushort* __restrict__ BhM,
    const float* __restrict__ zq, const float* __restrict__ nq,
    const float* __restrict__ zp, const float* __restrict__ npp,
    ushort* __restrict__ Vh){
  __shared__ __align__(16) float Q[128*33];
  __shared__ __align__(16) float P[32*33];
  __shared__ float nqs[128];
  __shared__ float nps[32];
  __shared__ __align__(16) ushort tAh[4096];
  __shared__ __align__(16) ushort tBh[4096];
  const int r0 = blockIdx.y * 128, c0 = blockIdx.x * 128;
  const int t = threadIdx.x;
  const int L = t & 63, w = t >> 6;
  const int wr = w >> 1, wc = w & 1;
  const int lm = L & 15, quad = L >> 4;
  const int sch = (t & 3) * 8;
  {
    const float* pr = zq + (size_t)(c0 + (t>>1)) * DD + (t&1) * 16;
    float* dr = &Q[(t>>1)*33 + (t&1)*16];
    #pragma unroll
    for (int u = 0; u < 4; u++){
      float4 a = ((const float4*)pr)[u];
      dr[4*u+0]=a.x; dr[4*u+1]=a.y; dr[4*u+2]=a.z; dr[4*u+3]=a.w;
    }
  }
  if (t < 128) nqs[t] = nq[c0 + t];
  const int gl = t & 31, gg0 = t >> 5;
  f32x4 acc[4][4];
  #pragma unroll
  for (int i = 0; i < 4; i++)
    #pragma unroll
    for (int j = 0; j < 4; j++) acc[i][j] = (f32x4){0.f, 0.f, 0.f, 0.f};

  for (int ks = 0; ks < NN; ks += 32){
    {
      const int prr = t >> 3, pcc = (t & 7) * 4;
      *(float4*)&P[prr*33 + pcc] = *(const float4*)(zp + (size_t)(ks + prr) * DD + pcc);
    }
    if (t < 32) nps[t] = npp[ks + t];
    #pragma unroll
    for (int p = 0; p < 2; p++){
      const int row = p*64 + (t >> 2);
      const size_t ga = (size_t)(r0 + row) * NN + ks + sch;
      const int lo = row*32 + sch;
      stage16(BhM + ga, tAh + lo);
    }
    __syncthreads();
    {
      const float* pv = &P[gl*33];
      const float npl = nps[gl];
      #pragma unroll 1
      for (int m = 0; m < 16; m++){
        const int gn = gg0 + 8*m;
        const float* qv = &Q[gn*33];
        float d = 0.f;
        #pragma unroll
        for (int k = 0; k < 32; k++) d = fmaf(qv[k], pv[k], d);
        tBh[gn*32 + gl] = f2bf(__expf(-(nqs[gn] + npl - 2.f*d) * (1.f/32.f)));
      }
    }
    __syncthreads();
    bf16x8 ah[4], bh[4];
    #pragma unroll
    for (int i = 0; i < 4; i++){
      const int ao = (wr*64 + i*16 + lm)*32 + quad*8;
      const int bo = (wc*64 + i*16 + lm)*32 + quad*8;
      ah[i] = *(const bf16x8*)&tAh[ao];
      bh[i] = *(const bf16x8*)&tBh[bo];
    }
    #pragma unroll
    for (int i = 0; i < 4; i++)
      #pragma unroll
      for (int j = 0; j < 4; j++)
        acc[i][j] = __builtin_amdgcn_mfma_f32_16x16x32_bf16(ah[i], bh[j], acc[i][j], 0, 0, 0);
    __syncthreads();
  }
  #pragma unroll
  for (int i = 0; i < 4; i++)
    #pragma unroll
    for (int j = 0; j < 4; j++)
      #pragma unroll
      for (int rg = 0; rg < 4; rg++){
        const int row = wr*64 + i*16 + quad*4 + rg;
        const int col = wc*64 + j*16 + lm;
        Vh[(size_t)(r0 + row) * NN + c0 + col] = f2bf(acc[i][j][rg]);
      }
}

// ---------------- blocked Gauss-Jordan: 512-thread diag block inverse (NB=128) ---------
__global__ __launch_bounds__(512) void k_gj_diag(float* __restrict__ M0, float* __restrict__ M1,
                                                 float* __restrict__ Pbuf,
                                                 ushort* __restrict__ Pth, ushort* __restrict__ Ptl,
                                                 int kb){
  float* M = blockIdx.x ? M1 : M0;
  float* P = Pbuf + (size_t)blockIdx.x * NB * NB;
  ushort* Ph = Pth + (size_t)blockIdx.x * NB * NB;
  ushort* Pl = Ptl + (size_t)blockIdx.x * NB * NB;
  __shared__ float rowbuf[NB];
  __shared__ float colbuf[NB];
  const int t = threadIdx.x;
  const int r = t >> 2, g = t & 3;
  const int k0 = kb * NB;
  float reg[32];
  #pragma unroll
  for (int j = 0; j < 32; j++) reg[j] = M[(size_t)(k0 + r) * NN + k0 + g + 4*j];
  __syncthreads();
  #pragma unroll 1
  for (int jj = 0; jj < NB; jj++){
    if (r == jj){
      #pragma unroll
      for (int j = 0; j < 32; j++) rowbuf[g + 4*j] = reg[j];
    }
    if (g == (jj & 3)) colbuf[r] = reg[jj >> 2];
    __syncthreads();
    const float p = 1.0f / rowbuf[jj];
    if (r == jj){
      #pragma unroll
      for (int j = 0; j < 32; j++){
        const int c = g + 4*j;
        reg[j] = (c == jj) ? p : reg[j] * p;
      }
    } else {
      const float f = colbuf[r] * p;
      #pragma unroll
      for (int j = 0; j < 32; j++){
        const int c = g + 4*j;
        reg[j] = (c == jj) ? (-f) : fmaf(-f, rowbuf[c], reg[j]);
      }
    }
    __syncthreads();
  }
  #pragma unroll
  for (int j = 0; j < 32; j++){
    const int c = g + 4*j;
    P[r * NB + c] = reg[j];
    ushort h = f2bf(reg[j]);
    Ph[(size_t)c * NB + r] = h;                 // transposed split
    Pl[(size_t)c * NB + r] = f2bf(reg[j] - bf2f(h));
  }
}

// Panel: T = P @ M[krow, :]; writes T fp32 + T^T split + C (col-panel) split
__global__ __launch_bounds__(256) void k_gj_panel(float* __restrict__ M0, float* __restrict__ M1,
                                                  const float* __restrict__ Pbuf,
                                                  float* __restrict__ Tf,
                                                  ushort* __restrict__ Tth, ushort* __restrict__ Ttl,
                                                  ushort* __restrict__ Chh, ushort* __restrict__ Chl,
                                                  int kb){
  const int mat = blockIdx.y;
  float* M = mat ? M1 : M0;
  const float* P = Pbuf + (size_t)mat * NB * NB;
  float* Tfm = Tf + (size_t)mat * NB * NN;
  ushort* Th = Tth + (size_t)mat * NN * NB;
  ushort* Tl = Ttl + (size_t)mat * NN * NB;
  ushort* Ch = Chh + (size_t)mat * NN * NB;
  ushort* Cl = Chl + (size_t)mat * NN * NB;
  const int jb = blockIdx.x;
  const int k0 = kb * NB, j0 = jb * NB;
  const int t = threadIdx.x;
  { // C split copy of M[:, kcol] panel (rows j0..j0+127)
    const int row = t >> 1, half = (t & 1) * 64;
    const float* src = M + (size_t)(j0 + row) * NN + k0 + half;
    ushort* dh = Ch + (size_t)(j0 + row) * NB + half;
    ushort* dl = Cl + (size_t)(j0 + row) * NB + half;
    #pragma unroll
    for (int u = 0; u < 16; u++){
      float4 v = ((const float4*)src)[u];
      ushort h0 = f2bf(v.x), h1 = f2bf(v.y), h2 = f2bf(v.z), h3 = f2bf(v.w);
      ((ushort4*)dh)[u] = make_ushort4(h0, h1, h2, h3);
      ((ushort4*)dl)[u] = make_ushort4(f2bf(v.x - bf2f(h0)), f2bf(v.y - bf2f(h1)),
                                       f2bf(v.z - bf2f(h2)), f2bf(v.w - bf2f(h3)));
    }
  }
  __shared__ float As[128 * 17];
  __shared__ float Bs[16 * 132];
  const int tx = t & 15, ty = t >> 4;
  const int lrow = t >> 1, lh = t & 1;
  float acc[8][8];
  #pragma unroll
  for (int u = 0; u < 8; u++)
    #pragma unroll
    for (int v = 0; v < 8; v++) acc[u][v] = 0.f;
  for (int ks = 0; ks < NB; ks += 16){
    {
      const float* pa = P + (size_t)lrow * NB + ks + lh * 8;
      float4 a0 = ((const float4*)pa)[0];
      float4 a1 = ((const float4*)pa)[1];
      float* da = &As[lrow * 17 + lh * 8];
      da[0]=a0.x; da[1]=a0.y; da[2]=a0.z; da[3]=a0.w;
      da[4]=a1.x; da[5]=a1.y; da[6]=a1.z; da[7]=a1.w;
      const int kkl = t >> 4, c8 = (t & 15) * 8;
      const float* pb = M + (size_t)(k0 + ks + kkl) * NN + j0 + c8;
      float4 b0 = ((const float4*)pb)[0];
      float4 b1 = ((const float4*)pb)[1];
      *(float4*)&Bs[kkl*132 + c8]     = b0;
      *(float4*)&Bs[kkl*132 + c8 + 4] = b1;
    }
    __syncthreads();
    #pragma unroll
    for (int kk = 0; kk < 16; kk++){
      float a[8], b[8];
      #pragma unroll
      for (int u = 0; u < 8; u++) a[u] = As[RMAP(ty,u)*17 + kk];
      float4 b0 = *(const float4*)&Bs[kk*132 + tx*4];
      float4 b1 = *(const float4*)&Bs[kk*132 + tx*4 + 64];
      b[0]=b0.x; b[1]=b0.y; b[2]=b0.z; b[3]=b0.w;
      b[4]=b1.x; b[5]=b1.y; b[6]=b1.z; b[7]=b1.w;
      #pragma unroll
      for (int u = 0; u < 8; u++)
        #pragma unroll
        for (int v = 0; v < 8; v++) acc[u][v] += a[u] * b[v];
    }
    __syncthreads();
  }
  // write T fp32 (coalesced) + T transposed split
  #pragma unroll
  for (int u = 0; u < 8; u++){
    const int rr = RMAP(ty,u);
    float* pd = Tfm + (size_t)rr * NN + j0 + tx*4;
    *(float4*)pd        = make_float4(acc[u][0], acc[u][1], acc[u][2], acc[u][3]);
    *(float4*)(pd + 64) = make_float4(acc[u][4], acc[u][5], acc[u][6], acc[u][7]);
    #pragma unroll
    for (int v = 0; v < 8; v++){
      const int cc = j0 + CMAP(tx,v);
      float val = acc[u][v];
      ushort h = f2bf(val);
      Th[(size_t)cc * NB + rr] = h;
      Tl[(size_t)cc * NB + rr] = f2bf(val - bf2f(h));
    }
  }
}

// Trailing update (MFMA split-3) + coalesced float4 RMW via LDS-transposed epilogue
__global__ __launch_bounds__(256) void k_gj_update(float* __restrict__ M0, float* __restrict__ M1,
    const float* __restrict__ Pbuf,
    const ushort* __restrict__ Pth, const ushort* __restrict__ Ptl,
    const float* __restrict__ Tf,
    const ushort* __restrict__ Tth, const ushort* __restrict__ Ttl,
    const ushort* __restrict__ Chh, const ushort* __restrict__ Chl, int kb){
  __shared__ __align__(16) float shbig[128 * 132];   // 67.6 KB; staging aliased below
  ushort* tAh = (ushort*)shbig;
  ushort* tAl = tAh + 4096;
  ushort* tBh = tAl + 4096;
  ushort* tBl = tBh + 4096;
  const int mat = blockIdx.z;
  float* M = mat ? M1 : M0;
  const float* P = Pbuf + (size_t)mat * NB * NB;
  const ushort* Ph = Pth + (size_t)mat * NB * NB;
  const ushort* Pl = Ptl + (size_t)mat * NB * NB;
  const float* Tfm = Tf + (size_t)mat * NB * NN;
  const ushort* Th = Tth + (size_t)mat * NN * NB;
  const ushort* Tl = Ttl + (size_t)mat * NN * NB;
  const ushort* Ch = Chh + (size_t)mat * NN * NB;
  const ushort* Cl = Chl + (size_t)mat * NN * NB;
  const int jb = blockIdx.x, ib = blockIdx.y;
  const int k0 = kb * NB, i0 = ib * NB, j0 = jb * NB;
  const int t = threadIdx.x;
  if (ib == kb){
    const int row = t >> 1, half = (t & 1) * 64;
    float* dst = M + (size_t)(k0 + row) * NN + j0 + half;
    if (jb == kb){
      const float* src = P + (size_t)row * NB + half;
      #pragma unroll
      for (int u = 0; u < 16; u++) ((float4*)dst)[u] = ((const float4*)src)[u];
    } else {
      const float* src = Tfm + (size_t)row * NN + j0 + half;
      #pragma unroll
      for (int u = 0; u < 16; u++) ((float4*)dst)[u] = ((const float4*)src)[u];
    }
    return;
  }
  const int L = t & 63, w = t >> 6;
  const int wr = w >> 1, wc = w & 1;
  const int lm = L & 15, quad = L >> 4;
  const int sch = (t & 3) * 8;
  const ushort* Bh = (jb == kb) ? Ph : (Th + (size_t)j0 * NB);
  const ushort* Bl = (jb == kb) ? Pl : (Tl + (size_t)j0 * NB);
  const ushort* Ahp = Ch + (size_t)i0 * NB;
  const ushort* Alp = Cl + (size_t)i0 * NB;
  f32x4 acc[4][4];
  #pragma unroll
  for (int i = 0; i < 4; i++)
    #pragma unroll
    for (int j = 0; j < 4; j++) acc[i][j] = (f32x4){0.f, 0.f, 0.f, 0.f};
  for (int ks = 0; ks < NB; ks += 32){
    #pragma unroll
    for (int p = 0; p < 2; p++){
      const int row = p*64 + (t >> 2);
      const size_t ga = (size_t)row * NB + ks + sch;
      const int lo = row*32 + sch;
      stage16(Ahp + ga, tAh + lo);
      stage16(Alp + ga, tAl + lo);
      stage16(Bh + ga, tBh + lo);
      stage16(Bl + ga, tBl + lo);
    }
    __syncthreads();
    bf16x8 ah[4], al[4], bh[4], bl[4];
    #pragma unroll
    for (int i = 0; i < 4; i++){
      const int ao = (wr*64 + i*16 + lm)*32 + quad*8;
      const int bo = (wc*64 + i*16 + lm)*32 + quad*8;
      ah[i] = *(const bf16x8*)&tAh[ao];
      al[i] = *(const bf16x8*)&tAl[ao];
      bh[i] = *(const bf16x8*)&tBh[bo];
      bl[i] = *(const bf16x8*)&tBl[bo];
    }
    #pragma unroll
    for (int i = 0; i < 4; i++)
      #pragma unroll
      for (int j = 0; j < 4; j++){
        acc[i][j] = __builtin_amdgcn_mfma_f32_16x16x32_bf16(ah[i], bh[j], acc[i][j], 0, 0, 0);
        acc[i][j] = __builtin_amdgcn_mfma_f32_16x16x32_bf16(ah[i], bl[j], acc[i][j], 0, 0, 0);
        acc[i][j] = __builtin_amdgcn_mfma_f32_16x16x32_bf16(al[i], bh[j], acc[i][j], 0, 0, 0);
      }
    __syncthreads();
  }
  // transpose C-layout acc through LDS for coalesced float4 global RMW
  #pragma unroll
  for (int i = 0; i < 4; i++)
    #pragma unroll
    for (int j = 0; j < 4; j++)
      #pragma unroll
      for (int rg = 0; rg < 4; rg++){
        const int row = wr*64 + i*16 + quad*4 + rg;
        const int col = wc*64 + j*16 + lm;
        shbig[row*132 + col] = acc[i][j][rg];
      }
  __syncthreads();
  const int rquad = t >> 2, cg = (t & 3) * 4;
  const int jc0 = (jb == kb) ? k0 : j0;
  if (jb == kb){
    #pragma unroll
    for (int p = 0; p < 2; p++){
      const int row = p*64 + rquad;
      float* pm = M + (size_t)(i0 + row) * NN + jc0;
      #pragma unroll
      for (int c = 0; c < 8; c++){
        const int col = cg + 16*c;
        float4 v = *(float4*)&shbig[row*132 + col];
        *(float4*)(pm + col) = make_float4(-v.x, -v.y, -v.z, -v.w);
      }
    }
  } else {
    #pragma unroll
    for (int p = 0; p < 2; p++){
      const int row = p*64 + rquad;
      float* pm = M + (size_t)(i0 + row) * NN + jc0;
      #pragma unroll
      for (int c = 0; c < 8; c++){
        const int col = cg + 16*c;
        float4 v = *(float4*)&shbig[row*132 + col];
        float4 m = *(float4*)(pm + col);
        m.x -= v.x; m.y -= v.y; m.z -= v.z; m.w -= v.w;
        *(float4*)(pm + col) = m;
      }
    }
  }
}

// ---------------- final combine ----------------
__global__ void k_combine(const float* __restrict__ slots, float* __restrict__ out){
  if (threadIdx.x == 0 && blockIdx.x == 0){
    const double invN2 = 1.0 / ((double)NN * (double)NN);
    double term1 = ((double)slots[0] + (double)slots[1] - 2.0 * (double)slots[2]) * invN2;
    double pairs = 0.0;
    for (int p = 0; p < 3; p++){
      const float* s = slots + 4 + 5 * p;
      pairs += ((double)s[0] - 0.2 * (double)s[1] + (double)s[2] - 0.2 * (double)s[3] - 2.0 * (double)s[4]);
    }
    out[0] = (float)(1.0 * term1 + 500.0 * pairs * invN2);
    out[1] = (float)((double)slots[3] / (2.0 * (double)NN));
  }
}

// ---------------- host ----------------
extern "C" void kernel_launch(void* const* d_in, const int* in_sizes, int n_in,
                              void* d_out, int out_size, void* d_ws, size_t ws_size,
                              hipStream_t stream){
  const float* x    = (const float*)d_in[0];
  const float* z    = (const float*)d_in[1];
  const float* zz   = (const float*)d_in[2];
  const float* xx   = (const float*)d_in[3];
  const float* stdn = (const float*)d_in[4];
  float* out = (float*)d_out;
  float* ws  = (float*)d_ws;

  const size_t NN2 = (size_t)NN * NN;
  float* R0 = ws;
  float* R1 = R0 + NN2;
  float* R2 = R1 + NN2;
  float* PanelF = R2 + NN2;
  ushort* Tth = (ushort*)PanelF;                       // 2 MB
  ushort* Ttl = Tth + 2 * (size_t)NB * NN;
  ushort* Chh = Ttl + 2 * (size_t)NB * NN;
  ushort* Chl = Chh + 2 * (size_t)NB * NN;             // panels total 8 MB
  float* Tf   = (float*)(Chl + 2 * (size_t)NB * NN);   // 4 MB fp32 T (2 mats)
  float* Pb   = Tf + 2 * (size_t)NB * NN;              // fp32 P (2 mats)
  ushort* Pth = (ushort*)(Pb + 2 * (size_t)NB * NB);
  ushort* Ptl = Pth + 2 * (size_t)NB * NB;
  float* slots= (float*)(Ptl + 2 * (size_t)NB * NB);
  float* stdsq= slots + 32;
  float* zrs  = stdsq + NN;
  float* nzz  = zrs + (size_t)NN * NV;
  float* nz8  = nzz + (size_t)NV * NN;
  float* nrmz = nz8 + (size_t)NV * NN;

  ushort* R0h = (ushort*)R0;   // B hi (bf16)
  ushort* R2h = (ushort*)R2;   // A hi (bf16)
  ushort* Vh  = (ushort*)R1;   // V hi (bf16)

  dim3 g32(NBLK, NBLK);

  k_zero<<<1, 64, 0, stream>>>(slots, 32);
  k_norms<<<(NN * NV) / 256, 256, 0, stream>>>(z, zz, stdn, stdsq, zrs, nzz, nz8);
  k_rownorm<<<NN / 256, 256, 0, stream>>>(nz8, nrmz);
  k_nll<<<1024, 256, 0, stream>>>(x, xx, slots);
  k_sqq<<<NTRI, 256, 0, stream>>>(z, nrmz, slots);
  k_spp_sqp<<<g32, 256, 0, stream>>>(stdn, stdsq, zrs, nrmz, slots);

  const float* zz0 = zz;            const float* z0 = z;
  const float* zz1 = zz + VD;       const float* z1 = z + VD;
  const float* nzz0 = nzz;          const float* nz0 = nz8;
  const float* nzz1 = nzz + NN;     const float* nz1 = nz8 + NN;

  for (int b = 1; b <= 2; b++){
    const float* zzb = zz + b*VD;  const float* nzzb = nzz + (size_t)b*NN;
    const float* zb  = z + b*VD;   const float* nzb  = nz8 + (size_t)b*NN;
    k_rbf<<<g32, 256, 0, stream>>>(zzb, zzb, nzzb, nzzb, 0.2f, R0);
    k_rbf<<<g32, 256, 0, stream>>>(zb,  zb,  nzb,  nzb,  0.2f, R1);
    for (int kb = 0; kb < NBLK; kb++){
      k_gj_diag<<<2, 512, 0, stream>>>(R0, R1, Pb, Pth, Ptl, kb);
      k_gj_panel<<<dim3(NBLK, 2), 256, 0, stream>>>(R0, R1, Pb, Tf, Tth, Ttl, Chh, Chl, kb);
      k_gj_update<<<dim3(NBLK, NBLK, 2), 256, 0, stream>>>(R0, R1, Pb, Pth, Ptl,
                                                           Tf, Tth, Ttl, Chh, Chl, kb);
    }
    // bf16 casts: A -> R2h, B -> R0h
    k_split<<<16384, 256, 0, stream>>>(R0, R2h);
    k_split<<<16384, 256, 0, stream>>>(R1, R0h);
    // V = B * Kpq (on-the-fly bf16 Kpq); dest R1
    k_mfma_vgen<<<g32, 256, 0, stream>>>(R0h, zzb, nzzb, zb, nzb, Vh);
    // trace GEMMs (pure bf16) with fused tr(L*A) reduction
    if (b == 1){
      k_mfma_tr<<<NTRI, 256, 0, stream>>>(R2h, R2h, 1, 1, 1,
                                          zz0, zz0, nzz0, nzz0, 5, 4,
                                          nullptr, nullptr, nullptr, nullptr, 0, 0, slots);
      k_mfma_tr<<<NTRI, 256, 0, stream>>>(R0h, R0h, 1, 1, 1,
                                          z0, z0, nz0, nz0, 7, 6,
                                          nullptr, nullptr, nullptr, nullptr, 0, 0, slots);
      k_mfma_tr<<<g32, 256, 0, stream>>>(R2h, Vh, 0, 0, 1,
                                         zz0, z0, nzz0, nz0, 8, 0,
                                         nullptr, nullptr, nullptr, nullptr, 0, 0, slots);
    } else {
      k_mfma_tr<<<NTRI, 256, 0, stream>>>(R2h, R2h, 1, 1, 2,
                                          zz1, zz1, nzz1, nzz1, 10, 9,
                                          zz0, zz0, nzz0, nzz0, 15, 14, slots);
      k_mfma_tr<<<NTRI, 256, 0, stream>>>(R0h, R0h, 1, 1, 2,
                                          z1, z1, nz1, nz1, 12, 11,
                                          z0, z0, nz0, nz0, 17, 16, slots);
      k_mfma_tr<<<g32, 256, 0, stream>>>(R2h, Vh, 0, 0, 2,
                                         zz1, z1, nzz1, nz1, 13, 0,
                                         zz0, z0, nzz0, nz0, 18, 0, slots);
    }
  }
  k_combine<<<1, 1, 0, stream>>>(slots, out);
}

// Round 11
// 29550.171 us; speedup vs baseline: 1.1628x; 1.0691x over previous
//
#include <hip/hip_runtime.h>
#include <math.h>

// Problem constants (fixed by setup_inputs)
#define NN 4096      // N samples
#define DD 256       // flat endo dim (8 vars * 32)
#define NV 8         // vars
#define VD 32        // per-var dim
#define NB 128       // GJ block size (reg[32]/512-thread diag is the proven config)
#define NBLK (NN/NB) // 32
#define NTRI (NBLK*(NBLK+1)/2)  // 528

// fp32-GEMM output ownership mapping (bank-conflict-free)
#define RMAP(ty,u) ((ty)*4 + (((u)>>2)<<6) + ((u)&3))
#define CMAP(tx,v) ((tx)*4 + (((v)>>2)<<6) + ((v)&3))

typedef __attribute__((ext_vector_type(8))) short bf16x8;
typedef __attribute__((ext_vector_type(4))) float f32x4;

#define AS1(p) ((const __attribute__((address_space(1))) void*)(p))
#define AS3(p) ((__attribute__((address_space(3))) void*)(p))

__device__ __forceinline__ void stage16(const ushort* g, ushort* l){
  __builtin_amdgcn_global_load_lds(AS1(g), AS3(l), 16, 0, 0);
}

__device__ __forceinline__ ushort f2bf(float x){
  uint u = __float_as_uint(x);
  u += 0x7FFFu + ((u >> 16) & 1u);
  return (ushort)(u >> 16);
}
__device__ __forceinline__ float bf2f(ushort h){ return __uint_as_float(((uint)h) << 16); }

// triangular block map: p -> (bi >= bj)
__device__ __forceinline__ void tri_map(int p, int& bi, int& bj){
  int b = (int)((sqrtf(8.0f * (float)p + 1.0f) - 1.0f) * 0.5f);
  while ((b + 1) * (b + 2) / 2 <= p) b++;
  while (b * (b + 1) / 2 > p) b--;
  bi = b; bj = p - b * (b + 1) / 2;
}

// ---------------- helpers ----------------
__device__ __forceinline__ void block_atomic_add(float v, float* red, float* dst){
  #pragma unroll
  for (int off = 32; off > 0; off >>= 1) v += __shfl_down(v, off, 64);
  const int lane = threadIdx.x & 63;
  const int w = threadIdx.x >> 6;
  if (lane == 0) red[w] = v;
  __syncthreads();
  if (threadIdx.x == 0) atomicAdd(dst, red[0] + red[1] + red[2] + red[3]);
  __syncthreads();
}

// ---------------- small utility kernels ----------------
__global__ void k_zero(float* p, int n){
  int i = blockIdx.x * blockDim.x + threadIdx.x;
  if (i < n) p[i] = 0.f;
}

__global__ void k_norms(const float* __restrict__ z, const float* __restrict__ zz,
                        const float* __restrict__ stdn,
                        float* __restrict__ stdsq, float* __restrict__ zrs,
                        float* __restrict__ nzz, float* __restrict__ nz8){
  int t = blockIdx.x * blockDim.x + threadIdx.x;
  if (t >= NN * NV) return;
  int i = t / NV, v = t % NV;
  const float* zp  = z  + (size_t)i * DD + v * VD;
  const float* zzp = zz + (size_t)i * DD + v * VD;
  float s1 = 0.f, s2 = 0.f, s2z = 0.f;
  #pragma unroll
  for (int k = 0; k < VD; k++){
    float a = zp[k];  s1 += a; s2 += a * a;
    float b = zzp[k]; s2z += b * b;
  }
  zrs[(size_t)i * NV + v] = s1;
  nz8[(size_t)v * NN + i] = s2;
  nzz[(size_t)v * NN + i] = s2z;
  if (v == 0){
    float s = 0.f;
    #pragma unroll
    for (int u = 0; u < NV; u++){ float a = stdn[(size_t)i * NV + u]; s += a * a; }
    stdsq[i] = s;
  }
}

__global__ void k_rownorm(const float* __restrict__ nz8, float* __restrict__ nrmz){
  int i = blockIdx.x * blockDim.x + threadIdx.x;
  if (i < NN){
    float s = 0.f;
    #pragma unroll
    for (int v = 0; v < NV; v++) s += nz8[(size_t)v * NN + i];
    nrmz[i] = s;
  }
}

__global__ __launch_bounds__(256) void k_nll(const float* __restrict__ x,
                                             const float* __restrict__ xx,
                                             float* __restrict__ slots){
  __shared__ float red[4];
  float s = 0.f;
  const int total = NN * DD;
  for (int i = (blockIdx.x * 256 + threadIdx.x) * 4; i < total; i += gridDim.x * 256 * 4){
    float4 a = *(const float4*)(x + i);
    float4 b = *(const float4*)(xx + i);
    float d0 = b.x - a.x, d1 = b.y - a.y, d2 = b.z - a.z, d3 = b.w - a.w;
    s += d0*d0 + d1*d1 + d2*d2 + d3*d3;
  }
  block_atomic_add(s, red, slots + 3);
}

// ---------------- first (exo-free) MMD term ----------------
__global__ __launch_bounds__(256) void k_sqq(const float* __restrict__ z,
                                             const float* __restrict__ nrm,
                                             float* __restrict__ slots){
  __shared__ float Xr[128 * 33];
  __shared__ float Xc[128 * 33];
  __shared__ float red[4];
  int bi, bj; tri_map(blockIdx.x, bi, bj);
  const int r0 = bi * 128, c0 = bj * 128;
  const float wgt = (bi != bj) ? 2.f : 1.f;
  const int t = threadIdx.x;
  const int tx = t & 15, ty = t >> 4;
  const int lrow = t >> 1, lh = t & 1;
  float acc[8][8];
  #pragma unroll
  for (int u = 0; u < 8; u++)
    #pragma unroll
    for (int v = 0; v < 8; v++) acc[u][v] = 0.f;
  for (int ks = 0; ks < DD; ks += 32){
    const float* pr = z + (size_t)(r0 + lrow) * DD + ks + lh * 16;
    const float* pc = z + (size_t)(c0 + lrow) * DD + ks + lh * 16;
    float* dr = &Xr[lrow * 33 + lh * 16];
    float* dc = &Xc[lrow * 33 + lh * 16];
    #pragma unroll
    for (int u = 0; u < 4; u++){
      float4 a = ((const float4*)pr)[u];
      dr[4*u+0] = a.x; dr[4*u+1] = a.y; dr[4*u+2] = a.z; dr[4*u+3] = a.w;
      float4 b = ((const float4*)pc)[u];
      dc[4*u+0] = b.x; dc[4*u+1] = b.y; dc[4*u+2] = b.z; dc[4*u+3] = b.w;
    }
    __syncthreads();
    #pragma unroll
    for (int kk = 0; kk < 32; kk++){
      float a[8], b[8];
      #pragma unroll
      for (int u = 0; u < 8; u++) a[u] = Xr[RMAP(ty,u)*33 + kk];
      #pragma unroll
      for (int v = 0; v < 8; v++) b[v] = Xc[CMAP(tx,v)*33 + kk];
      #pragma unroll
      for (int u = 0; u < 8; u++)
        #pragma unroll
        for (int v = 0; v < 8; v++) acc[u][v] += a[u] * b[v];
    }
    __syncthreads();
  }
  float s = 0.f;
  #pragma unroll 1
  for (int u = 0; u < 8; u++){
    const float ni = nrm[r0 + RMAP(ty,u)];
    #pragma unroll 1
    for (int v = 0; v < 8; v++)
      s += __expf(-(ni + nrm[c0 + CMAP(tx,v)] - 2.f * acc[u][v]) * (1.f/2048.f));
  }
  block_atomic_add(s * wgt, red, slots + 0);
}

__global__ __launch_bounds__(256) void k_spp_sqp(const float* __restrict__ stdn,
                                                 const float* __restrict__ stdsq,
                                                 const float* __restrict__ zrs,
                                                 const float* __restrict__ nrmz,
                                                 float* __restrict__ slots){
  __shared__ float sI[128*9], sJ[128*9], zI[128*9];
  __shared__ float qI[128], qJ[128], nI[128];
  __shared__ float red[4];
  const int r0 = blockIdx.y * 128, c0 = blockIdx.x * 128;
  const int t = threadIdx.x;
  if (t < 128){
    #pragma unroll
    for (int v = 0; v < 8; v++){
      sI[t*9+v] = stdn[(size_t)(r0+t)*NV + v];
      sJ[t*9+v] = stdn[(size_t)(c0+t)*NV + v];
      zI[t*9+v] = zrs[(size_t)(r0+t)*NV + v];
    }
    qI[t] = stdsq[r0+t]; qJ[t] = stdsq[c0+t]; nI[t] = nrmz[r0+t];
  }
  __syncthreads();
  const int tx = t & 15, ty = t >> 4;
  float spp = 0.f, sqp = 0.f;
  #pragma unroll 1
  for (int u = 0; u < 8; u++){
    int i = ty + 16*u;
    #pragma unroll 1
    for (int v = 0; v < 8; v++){
      int j = tx + 16*v;
      float dpp = 0.f, dqp = 0.f;
      #pragma unroll
      for (int k = 0; k < 8; k++){
        float sj = sJ[j*9+k];
        dpp += sI[i*9+k] * sj;
        dqp += zI[i*9+k] * sj;
      }
      spp += __expf(-(qI[i] + qJ[j] - 2.f*dpp) * (1.f/64.f));
      sqp += __expf(-(nI[i] + 32.f*qJ[j] - 2.f*dqp) * (1.f/2048.f));
    }
  }
  block_atomic_add(spp, red, slots + 1);
  block_atomic_add(sqp, red, slots + 2);
}

// ---------------- RBF Gram matrix build (K=32, fp32 out) ----------------
__global__ __launch_bounds__(256) void k_rbf(const float* __restrict__ Xr_,
                                             const float* __restrict__ Xc_,
                                             const float* __restrict__ nr,
                                             const float* __restrict__ nc,
                                             float lam, float* __restrict__ M){
  __shared__ float Xr[128 * 33];
  __shared__ float Xc[128 * 33];
  const int r0 = blockIdx.y * 128, c0 = blockIdx.x * 128;
  const int t = threadIdx.x;
  const int tx = t & 15, ty = t >> 4;
  const int lrow = t >> 1, lh = t & 1;
  {
    const float* pr = Xr_ + (size_t)(r0 + lrow) * DD + lh * 16;
    const float* pc = Xc_ + (size_t)(c0 + lrow) * DD + lh * 16;
    float* dr = &Xr[lrow * 33 + lh * 16];
    float* dc = &Xc[lrow * 33 + lh * 16];
    #pragma unroll
    for (int u = 0; u < 4; u++){
      float4 a = ((const float4*)pr)[u];
      dr[4*u+0]=a.x; dr[4*u+1]=a.y; dr[4*u+2]=a.z; dr[4*u+3]=a.w;
      float4 b = ((const float4*)pc)[u];
      dc[4*u+0]=b.x; dc[4*u+1]=b.y; dc[4*u+2]=b.z; dc[4*u+3]=b.w;
    }
  }
  __syncthreads();
  #pragma unroll 1
  for (int u = 0; u < 8; u++){
    const int gi = r0 + RMAP(ty,u);
    const float* xi = &Xr[RMAP(ty,u)*33];
    const float ni = nr[gi];
    float vals[8];
    #pragma unroll 1
    for (int v = 0; v < 8; v++){
      const int gj = c0 + CMAP(tx,v);
      const float* xj = &Xc[CMAP(tx,v)*33];
      float d = 0.f;
      #pragma unroll
      for (int k = 0; k < 32; k++) d += xi[k] * xj[k];
      float e = __expf(-(ni + nc[gj] - 2.f*d) * (1.f/32.f));
      if (gi == gj) e += lam;
      vals[v] = e;
    }
    float* pd = M + (size_t)gi * NN + c0 + tx*4;
    *(float4*)pd        = make_float4(vals[0], vals[1], vals[2], vals[3]);
    *(float4*)(pd + 64) = make_float4(vals[4], vals[5], vals[6], vals[7]);
  }
}

// ---------------- RBF Gram matrix build (K=32, bf16 out, no diag reg) ----------------
__global__ __launch_bounds__(256) void k_rbf16(const float* __restrict__ Xr_,
                                               const float* __restrict__ Xc_,
                                               const float* __restrict__ nr,
                                               const float* __restrict__ nc,
                                               ushort* __restrict__ Mh){
  __shared__ float Xr[128 * 33];
  __shared__ float Xc[128 * 33];
  const int r0 = blockIdx.y * 128, c0 = blockIdx.x * 128;
  const int t = threadIdx.x;
  const int tx = t & 15, ty = t >> 4;
  const int lrow = t >> 1, lh = t & 1;
  {
    const float* pr = Xr_ + (size_t)(r0 + lrow) * DD + lh * 16;
    const float* pc = Xc_ + (size_t)(c0 + lrow) * DD + lh * 16;
    float* dr = &Xr[lrow * 33 + lh * 16];
    float* dc = &Xc[lrow * 33 + lh * 16];
    #pragma unroll
    for (int u = 0; u < 4; u++){
      float4 a = ((const float4*)pr)[u];
      dr[4*u+0]=a.x; dr[4*u+1]=a.y; dr[4*u+2]=a.z; dr[4*u+3]=a.w;
      float4 b = ((const float4*)pc)[u];
      dc[4*u+0]=b.x; dc[4*u+1]=b.y; dc[4*u+2]=b.z; dc[4*u+3]=b.w;
    }
  }
  __syncthreads();
  #pragma unroll 1
  for (int u = 0; u < 8; u++){
    const int gi = r0 + RMAP(ty,u);
    const float* xi = &Xr[RMAP(ty,u)*33];
    const float ni = nr[gi];
    ushort vals[8];
    #pragma unroll 1
    for (int v = 0; v < 8; v++){
      const int gj = c0 + CMAP(tx,v);
      const float* xj = &Xc[CMAP(tx,v)*33];
      float d = 0.f;
      #pragma unroll
      for (int k = 0; k < 32; k++) d += xi[k] * xj[k];
      vals[v] = f2bf(__expf(-(ni + nc[gj] - 2.f*d) * (1.f/32.f)));
    }
    ushort* pd = Mh + (size_t)gi * NN + c0 + tx*4;
    *(ushort4*)pd        = make_ushort4(vals[0], vals[1], vals[2], vals[3]);
    *(ushort4*)(pd + 64) = make_ushort4(vals[4], vals[5], vals[6], vals[7]);
  }
}

// ---------------- fp32 -> bf16 (hi only; trace GEMMs run pure bf16) ----------------
__global__ __launch_bounds__(256) void k_split(const float* __restrict__ S,
                                               ushort* __restrict__ H){
  size_t i = ((size_t)blockIdx.x * 256 + threadIdx.x) * 4;
  float4 x = *(const float4*)(S + i);
  *(ushort4*)(H + i) = make_ushort4(f2bf(x.x), f2bf(x.y), f2bf(x.z), f2bf(x.w));
}

// ---------------- MFMA bf16 GEMM + fused RBF-trace epilogue(s) + fused tr(L*A) ----
__global__ __launch_bounds__(256) void k_mfma_tr(
    const ushort* __restrict__ Ah, const ushort* __restrict__ Bh,
    int sym, int doRed, int nepi,
    const float* e0xr, const float* e0xc, const float* e0nr, const float* e0nc, int s0, int rs0,
    const float* e1xr, const float* e1xc, const float* e1nr, const float* e1nc, int s1, int rs1,
    float* __restrict__ slots){
  __shared__ __align__(16) float shf[2*128*33 + 4];
  ushort* tAh = (ushort*)shf;
  ushort* tBh = tAh + 4096;
  float* red = shf + 2*128*33;
  int bi, bj;
  if (sym){ tri_map(blockIdx.x, bi, bj); } else { bi = blockIdx.y; bj = blockIdx.x; }
  const int r0 = bi * 128, c0 = bj * 128;
  const float wgt = (sym && bi != bj) ? 2.f : 1.f;
  const int t = threadIdx.x;
  const int L = t & 63, w = t >> 6;
  const int wr = w >> 1, wc = w & 1;
  const int lm = L & 15, quad = L >> 4;
  const int sch = (t & 3) * 8;

  f32x4 acc[4][4];
  #pragma unroll
  for (int i = 0; i < 4; i++)
    #pragma unroll
    for (int j = 0; j < 4; j++) acc[i][j] = (f32x4){0.f, 0.f, 0.f, 0.f};

  for (int ks = 0; ks < NN; ks += 32){
    #pragma unroll
    for (int p = 0; p < 2; p++){
      const int row = p*64 + (t >> 2);
      const size_t ga = (size_t)(r0 + row) * NN + ks + sch;
      const size_t gb = (size_t)(c0 + row) * NN + ks + sch;
      const int lo = row*32 + sch;
      stage16(Ah + ga, tAh + lo);
      stage16(Bh + gb, tBh + lo);
    }
    __syncthreads();
    bf16x8 ah[4], bh[4];
    #pragma unroll
    for (int i = 0; i < 4; i++){
      const int ao = (wr*64 + i*16 + lm)*32 + quad*8;
      const int bo = (wc*64 + i*16 + lm)*32 + quad*8;
      ah[i] = *(const bf16x8*)&tAh[ao];
      bh[i] = *(const bf16x8*)&tBh[bo];
    }
    #pragma unroll
    for (int i = 0; i < 4; i++)
      #pragma unroll
      for (int j = 0; j < 4; j++)
        acc[i][j] = __builtin_amdgcn_mfma_f32_16x16x32_bf16(ah[i], bh[j], acc[i][j], 0, 0, 0);
    __syncthreads();
  }

  float* Xr = shf;
  float* Xc = shf + 128*33;
  const int lrow = t >> 1, lh = t & 1;
  for (int e = 0; e < nepi; e++){
    const float* xr = e ? e1xr : e0xr;
    const float* xc = e ? e1xc : e0xc;
    const float* nr = e ? e1nr : e0nr;
    const float* nc = e ? e1nc : e0nc;
    const int slot = e ? s1 : s0;
    const int rslot = e ? rs1 : rs0;
    {
      const float* pr = xr + (size_t)(r0 + lrow) * DD + lh * 16;
      const float* pc = xc + (size_t)(c0 + lrow) * DD + lh * 16;
      float* dr = &Xr[lrow * 33 + lh * 16];
      float* dc = &Xc[lrow * 33 + lh * 16];
      #pragma unroll
      for (int u = 0; u < 4; u++){
        float4 a = ((const float4*)pr)[u];
        dr[4*u+0]=a.x; dr[4*u+1]=a.y; dr[4*u+2]=a.z; dr[4*u+3]=a.w;
        float4 b = ((const float4*)pc)[u];
        dc[4*u+0]=b.x; dc[4*u+1]=b.y; dc[4*u+2]=b.z; dc[4*u+3]=b.w;
      }
    }
    __syncthreads();
    float s = 0.f, s2 = 0.f;
    #pragma unroll 1
    for (int i = 0; i < 4; i++){
      #pragma unroll 1
      for (int rg = 0; rg < 4; rg++){
        const int rl = wr*64 + i*16 + quad*4 + rg;
        const float* xi = &Xr[rl*33];
        const float ni = nr[r0 + rl];
        #pragma unroll 1
        for (int j = 0; j < 4; j++){
          const int cl = wc*64 + j*16 + lm;
          const float* xj = &Xc[cl*33];
          float d = 0.f;
          #pragma unroll
          for (int k = 0; k < 32; k++) d = fmaf(xi[k], xj[k], d);
          const float Lval = __expf(-(ni + nc[c0 + cl] - 2.f*d) * (1.f/32.f));
          s += acc[i][j][rg] * Lval;
          if (doRed){
            const size_t o = (size_t)(r0 + rl) * NN + c0 + cl;
            s2 += bf2f(Ah[o]) * Lval;
          }
        }
      }
    }
    block_atomic_add(s * wgt, red, slots + slot);
    if (doRed) block_atomic_add(s2 * wgt, red, slots + rslot);
    __syncthreads();
  }
}

// ---------------- plain MFMA bf16 GEMM, bf16 store (V = B * QP^T-row layout) ----------
__global__ __launch_bounds__(256) void k_mfma_gemm(
    const ushort* __restrict__ Ah, const ushort* __restrict__ Bh,
    ushort* __restrict__ Dh){
  __shared__ __align__(16) ushort tAh[4096];
  __shared__ __align__(16) ushort tBh[4096];
  const int r0 = blockIdx.y * 128, c0 = blockIdx.x * 128;
  const int t = threadIdx.x;
  const int L = t & 63, w = t >> 6;
  const int wr = w >> 1, wc = w & 1;
  const int lm = L & 15, quad = L >> 4;
  const int sch = (t & 3) * 8;
  f32x4 acc[4][4];
  #pragma unroll
  for (int i = 0; i < 4; i++)
    #pragma unroll
    for (int j = 0; j < 4; j++) acc[i][j] = (f32x4){0.f, 0.f, 0.f, 0.f};
  for (int ks = 0; ks < NN; ks += 32){
    #pragma unroll
    for (int p = 0; p < 2; p++){
      const int row = p*64 + (t >> 2);
      const size_t ga = (size_t)(r0 + row) * NN + ks + sch;
      const size_t gb = (size_t)(c0 + row) * NN + ks + sch;
      const int lo = row*32 + sch;
      stage16(Ah + ga, tAh + lo);
      stage16(Bh + gb, tBh + lo);
    }
    __syncthreads();
    bf16x8 ah[4], bh[4];
    #pragma unroll
    for (int i = 0; i < 4; i++){
      const int ao = (wr*64 + i*16 + lm)*32 + quad*8;
      const int bo = (wc*64 + i*16 + lm)*32 + quad*8;
      ah[i] = *(const bf16x8*)&tAh[ao];
      bh[i] = *(const bf16x8*)&tBh[bo];
    }
    #pragma unroll
    for (int i = 0; i < 4; i++)
      #pragma unroll
      for (int j = 0; j < 4; j++)
        acc[i][j] = __builtin_amdgcn_mfma_f32_16x16x32_bf16(ah[i], bh[j], acc[i][j], 0, 0, 0);
    __syncthreads();
  }
  #pragma unroll
  for (int i = 0; i < 4; i++)
    #pragma unroll
    for (int j = 0; j < 4; j++)
      #pragma unroll
      for (int rg = 0; rg < 4; rg++){
        const int row = wr*64 + i*16 + quad*4 + rg;
        const int col = wc*64 + j*16 + lm;
        Dh[(size_t)(r0 + row) * NN + c0 + col] = f2bf(acc[i][j][rg]);
      }
}

// ---------------- fused GJ diag + panel (512 threads, grid 16 x 2mats) ----------------
// Every block redundantly runs the proven reg[32] register GJ of the 128x128 diag block,
// deposits P into LDS; block.x==0 also writes P / P^T-split to global (for k_gj_update).
// Then each 256-thread half runs the panel GEMM (T = P @ M[krow,:]) on its own j-tile,
// reading the A operand directly from LDS-P, and writes T fp32 + T^T split + C split.
__global__ __launch_bounds__(512) void k_gj_diagpanel(
    float* __restrict__ M0, float* __restrict__ M1,
    float* __restrict__ Pbuf, ushort* __restrict__ Pth, ushort* __restrict__ Ptl,
    float* __restrict__ Tf, ushort* __restrict__ Tth, ushort* __restrict__ Ttl,
    ushort* __restrict__ Chh, ushort* __restrict__ Chl, int kb){
  __shared__ float Ps[128 * 132];
  __shared__ float rowbuf[NB];
  __shared__ float colbuf[NB];
  __shared__ float Bs[2][16 * 132];
  const int mat = blockIdx.y;
  float* M = mat ? M1 : M0;
  float* P = Pbuf + (size_t)mat * NB * NB;
  ushort* Ph = Pth + (size_t)mat * NB * NB;
  ushort* Pl = Ptl + (size_t)mat * NB * NB;
  float* Tfm = Tf + (size_t)mat * NB * NN;
  ushort* Th = Tth + (size_t)mat * NN * NB;
  ushort* Tl = Ttl + (size_t)mat * NN * NB;
  ushort* Ch = Chh + (size_t)mat * NN * NB;
  ushort* Cl = Chl + (size_t)mat * NN * NB;
  const int k0 = kb * NB;
  const int t = threadIdx.x;
  // ---- register GJ diag (proven layout: r = t>>2, g = t&3, reg[32]) ----
  {
    const int r = t >> 2, g = t & 3;
    float reg[32];
    #pragma unroll
    for (int j = 0; j < 32; j++) reg[j] = M[(size_t)(k0 + r) * NN + k0 + g + 4*j];
    __syncthreads();
    #pragma unroll 1
    for (int jj = 0; jj < NB; jj++){
      if (r == jj){
        #pragma unroll
        for (int j = 0; j < 32; j++) rowbuf[g + 4*j] = reg[j];
      }
      if (g == (jj & 3)) colbuf[r] = reg[jj >> 2];
      __syncthreads();
      const float p = 1.0f / rowbuf[jj];
      if (r == jj){
        #pragma unroll
        for (int j = 0; j < 32; j++){
          const int c = g + 4*j;
          reg[j] = (c == jj) ? p : reg[j] * p;
        }
      } else {
        const float f = colbuf[r] * p;
        #pragma unroll
        for (int j = 0; j < 32; j++){
          const int c = g + 4*j;
          reg[j] = (c == jj) ? (-f) : fmaf(-f, rowbuf[c], reg[j]);
        }
      }
      __syncthreads();
    }
    #pragma unroll
    for (int j = 0; j < 32; j++){
      const int c = g + 4*j;
      Ps[r*132 + c] = reg[j];
    }
    if (blockIdx.x == 0){
      #pragma unroll
      for (int j = 0; j < 32; j++){
        const int c = g + 4*j;
        P[r * NB + c] = reg[j];
        ushort h = f2bf(reg[j]);
        Ph[(size_t)c * NB + r] = h;
        Pl[(size_t)c * NB + r] = f2bf(reg[j] - bf2f(h));
      }
    }
  }
  __syncthreads();
  // ---- panel GEMM: 2 j-tiles per block, one per 256-thread half ----
  const int half = t >> 8, tt = t & 255;
  const int j0 = blockIdx.x * 256 + half * 128;
  { // C split copy of M[:, kcol] panel (rows j0..j0+127) - pre-update values
    const int row = tt >> 1, hc = (tt & 1) * 64;
    const float* src = M + (size_t)(j0 + row) * NN + k0 + hc;
    ushort* dh = Ch + (size_t)(j0 + row) * NB + hc;
    ushort* dl = Cl + (size_t)(j0 + row) * NB + hc;
    #pragma unroll
    for (int u = 0; u < 16; u++){
      float4 v = ((const float4*)src)[u];
      ushort h0 = f2bf(v.x), h1 = f2bf(v.y), h2 = f2bf(v.z), h3 = f2bf(v.w);
      ((ushort4*)dh)[u] = make_ushort4(h0, h1, h2, h3);
      ((ushort4*)dl)[u] = make_ushort4(f2bf(v.x - bf2f(h0)), f2bf(v.y - bf2f(h1)),
                                       f2bf(v.z - bf2f(h2)), f2bf(v.w - bf2f(h3)));
    }
  }
  const int tx = tt & 15, ty = tt >> 4;
  float* myBs = Bs[half];
  float acc[8][8];
  #pragma unroll
  for (int u = 0; u < 8; u++)
    #pragma unroll
    for (int v = 0; v < 8; v++) acc[u][v] = 0.f;
  for (int ks = 0; ks < NB; ks += 16){
    {
      const int kkl = tt >> 4, c8 = (tt & 15) * 8;
      const float* pb = M + (size_t)(k0 + ks + kkl) * NN + j0 + c8;
      float4 b0 = ((const float4*)pb)[0];
      float4 b1 = ((const float4*)pb)[1];
      *(float4*)&myBs[kkl*132 + c8]     = b0;
      *(float4*)&myBs[kkl*132 + c8 + 4] = b1;
    }
    __syncthreads();
    #pragma unroll
    for (int kk = 0; kk < 16; kk++){
      float a[8], b[8];
      #pragma unroll
      for (int u = 0; u < 8; u++) a[u] = Ps[RMAP(ty,u)*132 + ks + kk];
      float4 b0 = *(const float4*)&myBs[kk*132 + tx*4];
      float4 b1 = *(const float4*)&myBs[kk*132 + tx*4 + 64];
      b[0]=b0.x; b[1]=b0.y; b[2]=b0.z; b[3]=b0.w;
      b[4]=b1.x; b[5]=b1.y; b[6]=b1.z; b[7]=b1.w;
      #pragma unroll
      for (int u = 0; u < 8; u++)
        #pragma unroll
        for (int v = 0; v < 8; v++) acc[u][v] += a[u] * b[v];
    }
    __syncthreads();
  }
  // write T fp32 (coalesced) + T transposed split
  #pragma unroll
  for (int u = 0; u < 8; u++){
    const int rr = RMAP(ty,u);
    float* pd = Tfm + (size_t)rr * NN + j0 + tx*4;
    *(float4*)pd        = make_float4(acc[u][0], acc[u][1], acc[u][2], acc[u][3]);
    *(float4*)(pd + 64) = make_float4(acc[u][4], acc[u][5], acc[u][6], acc[u][7]);
    #pragma unroll
    for (int v = 0; v < 8; v++){
      const int cc = j0 + CMAP(tx,v);
      float val = acc[u][v];
      ushort h = f2bf(val);
      Th[(size_t)cc * NB + rr] = h;
      Tl[(size_t)cc * NB + rr] = f2bf(val - bf2f(h));
    }
  }
}

// Trailing update (MFMA split-3) + coalesced float4 RMW via LDS-transposed epilogue
__global__ __launch_bounds__(256) void k_gj_update(float* __restrict__ M0, float* __restrict__ M1,
    const float* __restrict__ Pbuf,
    const ushort* __restrict__ Pth, const ushort* __restrict__ Ptl,
    const float* __restrict__ Tf,
    const ushort* __restrict__ Tth, const ushort* __restrict__ Ttl,
    const ushort* __restrict__ Chh, const ushort* __restrict__ Chl, int kb){
  __shared__ __align__(16) float shbig[128 * 132];   // 67.6 KB; staging aliased below
  ushort* tAh = (ushort*)shbig;
  ushort* tAl = tAh + 4096;
  ushort* tBh = tAl + 4096;
  ushort* tBl = tBh + 4096;
  const int mat = blockIdx.z;
  float* M = mat ? M1 : M0;
  const float* P = Pbuf + (size_t)mat * NB * NB;
  const ushort* Ph = Pth + (size_t)mat * NB * NB;
  const ushort* Pl = Ptl + (size_t)mat * NB * NB;
  const float* Tfm = Tf + (size_t)mat * NB * NN;
  const ushort* Th = Tth + (size_t)mat * NN * NB;
  const ushort* Tl = Ttl + (size_t)mat * NN * NB;
  const ushort* Ch = Chh + (size_t)mat * NN * NB;
  const ushort* Cl = Chl + (size_t)mat * NN * NB;
  const int jb = blockIdx.x, ib = blockIdx.y;
  const int k0 = kb * NB, i0 = ib * NB, j0 = jb * NB;
  const int t = threadIdx.x;
  if (ib == kb){
    const int row = t >> 1, half = (t & 1) * 64;
    float* dst = M + (size_t)(k0 + row) * NN + j0 + half;
    if (jb == kb){
      const float* src = P + (size_t)row * NB + half;
      #pragma unroll
      for (int u = 0; u < 16; u++) ((float4*)dst)[u] = ((const float4*)src)[u];
    } else {
      const float* src = Tfm + (size_t)row * NN + j0 + half;
      #pragma unroll
      for (int u = 0; u < 16; u++) ((float4*)dst)[u] = ((const float4*)src)[u];
    }
    return;
  }
  const int L = t & 63, w = t >> 6;
  const int wr = w >> 1, wc = w & 1;
  const int lm = L & 15, quad = L >> 4;
  const int sch = (t & 3) * 8;
  const ushort* Bh = (jb == kb) ? Ph : (Th + (size_t)j0 * NB);
  const ushort* Bl = (jb == kb) ? Pl : (Tl + (size_t)j0 * NB);
  const ushort* Ahp = Ch + (size_t)i0 * NB;
  const ushort* Alp = Cl + (size_t)i0 * NB;
  f32x4 acc[4][4];
  #pragma unroll
  for (int i = 0; i < 4; i++)
    #pragma unroll
    for (int j = 0; j < 4; j++) acc[i][j] = (f32x4){0.f, 0.f, 0.f, 0.f};
  for (int ks = 0; ks < NB; ks += 32){
    #pragma unroll
    for (int p = 0; p < 2; p++){
      const int row = p*64 + (t >> 2);
      const size_t ga = (size_t)row * NB + ks + sch;
      const int lo = row*32 + sch;
      stage16(Ahp + ga, tAh + lo);
      stage16(Alp + ga, tAl + lo);
      stage16(Bh + ga, tBh + lo);
      stage16(Bl + ga, tBl + lo);
    }
    __syncthreads();
    bf16x8 ah[4], al[4], bh[4], bl[4];
    #pragma unroll
    for (int i = 0; i < 4; i++){
      const int ao = (wr*64 + i*16 + lm)*32 + quad*8;
      const int bo = (wc*64 + i*16 + lm)*32 + quad*8;
      ah[i] = *(const bf16x8*)&tAh[ao];
      al[i] = *(const bf16x8*)&tAl[ao];
      bh[i] = *(const bf16x8*)&tBh[bo];
      bl[i] = *(const bf16x8*)&tBl[bo];
    }
    #pragma unroll
    for (int i = 0; i < 4; i++)
      #pragma unroll
      for (int j = 0; j < 4; j++){
        acc[i][j] = __builtin_amdgcn_mfma_f32_16x16x32_bf16(ah[i], bh[j], acc[i][j], 0, 0, 0);
        acc[i][j] = __builtin_amdgcn_mfma_f32_16x16x32_bf16(ah[i], bl[j], acc[i][j], 0, 0, 0);
        acc[i][j] = __builtin_amdgcn_mfma_f32_16x16x32_bf16(al[i], bh[j], acc[i][j], 0, 0, 0);
      }
    __syncthreads();
  }
  // transpose C-layout acc through LDS for coalesced float4 global RMW
  #pragma unroll
  for (int i = 0; i < 4; i++)
    #pragma unroll
    for (int j = 0; j < 4; j++)
      #pragma unroll
      for (int rg = 0; rg < 4; rg++){
        const int row = wr*64 + i*16 + quad*4 + rg;
        const int col = wc*64 + j*16 + lm;
        shbig[row*132 + col] = acc[i][j][rg];
      }
  __syncthreads();
  const int rquad = t >> 2, cg = (t & 3) * 4;
  const int jc0 = (jb == kb) ? k0 : j0;
  if (jb == kb){
    #pragma unroll
    for (int p = 0; p < 2; p++){
      const int row = p*64 + rquad;
      float* pm = M + (size_t)(i0 + row) * NN + jc0;
      #pragma unroll
      for (int c = 0; c < 8; c++){
        const int col = cg + 16*c;
        float4 v = *(float4*)&shbig[row*132 + col];
        *(float4*)(pm + col) = make_float4(-v.x, -v.y, -v.z, -v.w);
      }
    }
  } else {
    #pragma unroll
    for (int p = 0; p < 2; p++){
      const int row = p*64 + rquad;
      float* pm = M + (size_t)(i0 + row) * NN + jc0;
      #pragma unroll
      for (int c = 0; c < 8; c++){
        const int col = cg + 16*c;
        float4 v = *(float4*)&shbig[row*132 + col];
        float4 m = *(float4*)(pm + col);
        m.x -= v.x; m.y -= v.y; m.z -= v.z; m.w -= v.w;
        *(float4*)(pm + col) = m;
      }
    }
  }
}

// ---------------- final combine ----------------
__global__ void k_combine(const float* __restrict__ slots, float* __restrict__ out){
  if (threadIdx.x == 0 && blockIdx.x == 0){
    const double invN2 = 1.0 / ((double)NN * (double)NN);
    double term1 = ((double)slots[0] + (double)slots[1] - 2.0 * (double)slots[2]) * invN2;
    double pairs = 0.0;
    for (int p = 0; p < 3; p++){
      const float* s = slots + 4 + 5 * p;
      pairs += ((double)s[0] - 0.2 * (double)s[1] + (double)s[2] - 0.2 * (double)s[3] - 2.0 * (double)s[4]);
    }
    out[0] = (float)(1.0 * term1 + 500.0 * pairs * invN2);
    out[1] = (float)((double)slots[3] / (2.0 * (double)NN));
  }
}

// ---------------- host ----------------
extern "C" void kernel_launch(void* const* d_in, const int* in_sizes, int n_in,
                              void* d_out, int out_size, void* d_ws, size_t ws_size,
                              hipStream_t stream){
  const float* x    = (const float*)d_in[0];
  const float* z    = (const float*)d_in[1];
  const float* zz   = (const float*)d_in[2];
  const float* xx   = (const float*)d_in[3];
  const float* stdn = (const float*)d_in[4];
  float* out = (float*)d_out;
  float* ws  = (float*)d_ws;

  const size_t NN2 = (size_t)NN * NN;
  float* R0 = ws;
  float* R1 = R0 + NN2;
  float* R2 = R1 + NN2;
  float* PanelF = R2 + NN2;
  ushort* Tth = (ushort*)PanelF;                       // 2 MB
  ushort* Ttl = Tth + 2 * (size_t)NB * NN;
  ushort* Chh = Ttl + 2 * (size_t)NB * NN;
  ushort* Chl = Chh + 2 * (size_t)NB * NN;             // panels total 8 MB
  float* Tf   = (float*)(Chl + 2 * (size_t)NB * NN);   // 4 MB fp32 T (2 mats)
  float* Pb   = Tf + 2 * (size_t)NB * NN;              // fp32 P (2 mats)
  ushort* Pth = (ushort*)(Pb + 2 * (size_t)NB * NB);
  ushort* Ptl = Pth + 2 * (size_t)NB * NB;
  float* slots= (float*)(Ptl + 2 * (size_t)NB * NB);
  float* stdsq= slots + 32;
  float* zrs  = stdsq + NN;
  float* nzz  = zrs + (size_t)NN * NV;
  float* nz8  = nzz + (size_t)NV * NN;
  float* nrmz = nz8 + (size_t)NV * NN;

  ushort* R0h = (ushort*)R0;   // B hi (bf16)
  ushort* R2h = (ushort*)R2;   // A hi (bf16)
  ushort* Vh  = (ushort*)R1;   // V hi (bf16, lower half of R1)
  ushort* QPh = Vh + NN2;      // Kqp bf16 (upper half of R1)

  dim3 g32(NBLK, NBLK);

  k_zero<<<1, 64, 0, stream>>>(slots, 32);
  k_norms<<<(NN * NV) / 256, 256, 0, stream>>>(z, zz, stdn, stdsq, zrs, nzz, nz8);
  k_rownorm<<<NN / 256, 256, 0, stream>>>(nz8, nrmz);
  k_nll<<<1024, 256, 0, stream>>>(x, xx, slots);
  k_sqq<<<NTRI, 256, 0, stream>>>(z, nrmz, slots);
  k_spp_sqp<<<g32, 256, 0, stream>>>(stdn, stdsq, zrs, nrmz, slots);

  const float* zz0 = zz;            const float* z0 = z;
  const float* zz1 = zz + VD;       const float* z1 = z + VD;
  const float* nzz0 = nzz;          const float* nz0 = nz8;
  const float* nzz1 = nzz + NN;     const float* nz1 = nz8 + NN;

  for (int b = 1; b <= 2; b++){
    const float* zzb = zz + b*VD;  const float* nzzb = nzz + (size_t)b*NN;
    const float* zb  = z + b*VD;   const float* nzb  = nz8 + (size_t)b*NN;
    k_rbf<<<g32, 256, 0, stream>>>(zzb, zzb, nzzb, nzzb, 0.2f, R0);
    k_rbf<<<g32, 256, 0, stream>>>(zb,  zb,  nzb,  nzb,  0.2f, R1);
    for (int kb = 0; kb < NBLK; kb++){
      k_gj_diagpanel<<<dim3(16, 2), 512, 0, stream>>>(R0, R1, Pb, Pth, Ptl,
                                                      Tf, Tth, Ttl, Chh, Chl, kb);
      k_gj_update<<<dim3(NBLK, NBLK, 2), 256, 0, stream>>>(R0, R1, Pb, Pth, Ptl,
                                                           Tf, Tth, Ttl, Chh, Chl, kb);
    }
    // bf16 casts: A -> R2h, B -> R0h (B fp32 in R1 dead after)
    k_split<<<16384, 256, 0, stream>>>(R0, R2h);
    k_split<<<16384, 256, 0, stream>>>(R1, R0h);
    // Kqp bf16 precompute: QP[n][l] = k(zz_n, z_l), into upper half of R1
    k_rbf16<<<g32, 256, 0, stream>>>(zzb, zb, nzzb, nzb, QPh);
    // V = B * QP^T (plain bf16 GEMM); dest Vh (lower half of R1)
    k_mfma_gemm<<<g32, 256, 0, stream>>>(R0h, QPh, Vh);
    // trace GEMMs (pure bf16) with fused tr(L*A) reduction
    if (b == 1){
      k_mfma_tr<<<NTRI, 256, 0, stream>>>(R2h, R2h, 1, 1, 1,
                                          zz0, zz0, nzz0, nzz0, 5, 4,
                                          nullptr, nullptr, nullptr, nullptr, 0, 0, slots);
      k_mfma_tr<<<NTRI, 256, 0, stream>>>(R0h, R0h, 1, 1, 1,
                                          z0, z0, nz0, nz0, 7, 6,
                                          nullptr, nullptr, nullptr, nullptr, 0, 0, slots);
      k_mfma_tr<<<g32, 256, 0, stream>>>(R2h, Vh, 0, 0, 1,
                                         zz0, z0, nzz0, nz0, 8, 0,
                                         nullptr, nullptr, nullptr, nullptr, 0, 0, slots);
    } else {
      k_mfma_tr<<<NTRI, 256, 0, stream>>>(R2h, R2h, 1, 1, 2,
                                          zz1, zz1, nzz1, nzz1, 10, 9,
                                          zz0, zz0, nzz0, nzz0, 15, 14, slots);
      k_mfma_tr<<<NTRI, 256, 0, stream>>>(R0h, R0h, 1, 1, 2,
                                          z1, z1, nz1, nz1, 12, 11,
                                          z0, z0, nz0, nz0, 17, 16, slots);
      k_mfma_tr<<<g32, 256, 0, stream>>>(R2h, Vh, 0, 0, 2,
                                         zz1, z1, nzz1, nz1, 13, 0,
                                         zz0, z0, nzz0, nz0, 18, 0, slots);
    }
  }
  k_combine<<<1, 1, 0, stream>>>(slots, out);
}

// Round 12
// 29490.207 us; speedup vs baseline: 1.1651x; 1.0020x over previous
//
#include <hip/hip_runtime.h>
#include <math.h>

// Problem constants (fixed by setup_inputs)
#define NN 4096      // N samples
#define DD 256       // flat endo dim (8 vars * 32)
#define NV 8         // vars
#define VD 32        // per-var dim
#define NB 128       // GJ block size (reg[32]/512-thread diag is the proven config)
#define NBLK (NN/NB) // 32
#define NTRI (NBLK*(NBLK+1)/2)  // 528

// fp32-GEMM output ownership mapping (bank-conflict-free)
#define RMAP(ty,u) ((ty)*4 + (((u)>>2)<<6) + ((u)&3))
#define CMAP(tx,v) ((tx)*4 + (((v)>>2)<<6) + ((v)&3))

typedef __attribute__((ext_vector_type(8))) short bf16x8;
typedef __attribute__((ext_vector_type(4))) float f32x4;

#define AS1(p) ((const __attribute__((address_space(1))) void*)(p))
#define AS3(p) ((__attribute__((address_space(3))) void*)(p))

__device__ __forceinline__ void stage16(const ushort* g, ushort* l){
  __builtin_amdgcn_global_load_lds(AS1(g), AS3(l), 16, 0, 0);
}

__device__ __forceinline__ ushort f2bf(float x){
  uint u = __float_as_uint(x);
  u += 0x7FFFu + ((u >> 16) & 1u);
  return (ushort)(u >> 16);
}
__device__ __forceinline__ float bf2f(ushort h){ return __uint_as_float(((uint)h) << 16); }

// triangular block map: p -> (bi >= bj)
__device__ __forceinline__ void tri_map(int p, int& bi, int& bj){
  int b = (int)((sqrtf(8.0f * (float)p + 1.0f) - 1.0f) * 0.5f);
  while ((b + 1) * (b + 2) / 2 <= p) b++;
  while (b * (b + 1) / 2 > p) b--;
  bi = b; bj = p - b * (b + 1) / 2;
}

// ---------------- helpers ----------------
__device__ __forceinline__ void block_atomic_add(float v, float* red, float* dst){
  #pragma unroll
  for (int off = 32; off > 0; off >>= 1) v += __shfl_down(v, off, 64);
  const int lane = threadIdx.x & 63;
  const int w = threadIdx.x >> 6;
  if (lane == 0) red[w] = v;
  __syncthreads();
  if (threadIdx.x == 0) atomicAdd(dst, red[0] + red[1] + red[2] + red[3]);
  __syncthreads();
}

// ---------------- small utility kernels ----------------
__global__ void k_zero(float* p, int n){
  int i = blockIdx.x * blockDim.x + threadIdx.x;
  if (i < n) p[i] = 0.f;
}

__global__ void k_norms(const float* __restrict__ z, const float* __restrict__ zz,
                        const float* __restrict__ stdn,
                        float* __restrict__ stdsq, float* __restrict__ zrs,
                        float* __restrict__ nzz, float* __restrict__ nz8){
  int t = blockIdx.x * blockDim.x + threadIdx.x;
  if (t >= NN * NV) return;
  int i = t / NV, v = t % NV;
  const float* zp  = z  + (size_t)i * DD + v * VD;
  const float* zzp = zz + (size_t)i * DD + v * VD;
  float s1 = 0.f, s2 = 0.f, s2z = 0.f;
  #pragma unroll
  for (int k = 0; k < VD; k++){
    float a = zp[k];  s1 += a; s2 += a * a;
    float b = zzp[k]; s2z += b * b;
  }
  zrs[(size_t)i * NV + v] = s1;
  nz8[(size_t)v * NN + i] = s2;
  nzz[(size_t)v * NN + i] = s2z;
  if (v == 0){
    float s = 0.f;
    #pragma unroll
    for (int u = 0; u < NV; u++){ float a = stdn[(size_t)i * NV + u]; s += a * a; }
    stdsq[i] = s;
  }
}

__global__ void k_rownorm(const float* __restrict__ nz8, float* __restrict__ nrmz){
  int i = blockIdx.x * blockDim.x + threadIdx.x;
  if (i < NN){
    float s = 0.f;
    #pragma unroll
    for (int v = 0; v < NV; v++) s += nz8[(size_t)v * NN + i];
    nrmz[i] = s;
  }
}

__global__ __launch_bounds__(256) void k_nll(const float* __restrict__ x,
                                             const float* __restrict__ xx,
                                             float* __restrict__ slots){
  __shared__ float red[4];
  float s = 0.f;
  const int total = NN * DD;
  for (int i = (blockIdx.x * 256 + threadIdx.x) * 4; i < total; i += gridDim.x * 256 * 4){
    float4 a = *(const float4*)(x + i);
    float4 b = *(const float4*)(xx + i);
    float d0 = b.x - a.x, d1 = b.y - a.y, d2 = b.z - a.z, d3 = b.w - a.w;
    s += d0*d0 + d1*d1 + d2*d2 + d3*d3;
  }
  block_atomic_add(s, red, slots + 3);
}

// ---------------- first (exo-free) MMD term ----------------
__global__ __launch_bounds__(256) void k_sqq(const float* __restrict__ z,
                                             const float* __restrict__ nrm,
                                             float* __restrict__ slots){
  __shared__ float Xr[128 * 33];
  __shared__ float Xc[128 * 33];
  __shared__ float red[4];
  int bi, bj; tri_map(blockIdx.x, bi, bj);
  const int r0 = bi * 128, c0 = bj * 128;
  const float wgt = (bi != bj) ? 2.f : 1.f;
  const int t = threadIdx.x;
  const int tx = t & 15, ty = t >> 4;
  const int lrow = t >> 1, lh = t & 1;
  float acc[8][8];
  #pragma unroll
  for (int u = 0; u < 8; u++)
    #pragma unroll
    for (int v = 0; v < 8; v++) acc[u][v] = 0.f;
  for (int ks = 0; ks < DD; ks += 32){
    const float* pr = z + (size_t)(r0 + lrow) * DD + ks + lh * 16;
    const float* pc = z + (size_t)(c0 + lrow) * DD + ks + lh * 16;
    float* dr = &Xr[lrow * 33 + lh * 16];
    float* dc = &Xc[lrow * 33 + lh * 16];
    #pragma unroll
    for (int u = 0; u < 4; u++){
      float4 a = ((const float4*)pr)[u];
      dr[4*u+0] = a.x; dr[4*u+1] = a.y; dr[4*u+2] = a.z; dr[4*u+3] = a.w;
      float4 b = ((const float4*)pc)[u];
      dc[4*u+0] = b.x; dc[4*u+1] = b.y; dc[4*u+2] = b.z; dc[4*u+3] = b.w;
    }
    __syncthreads();
    #pragma unroll
    for (int kk = 0; kk < 32; kk++){
      float a[8], b[8];
      #pragma unroll
      for (int u = 0; u < 8; u++) a[u] = Xr[RMAP(ty,u)*33 + kk];
      #pragma unroll
      for (int v = 0; v < 8; v++) b[v] = Xc[CMAP(tx,v)*33 + kk];
      #pragma unroll
      for (int u = 0; u < 8; u++)
        #pragma unroll
        for (int v = 0; v < 8; v++) acc[u][v] += a[u] * b[v];
    }
    __syncthreads();
  }
  float s = 0.f;
  #pragma unroll 1
  for (int u = 0; u < 8; u++){
    const float ni = nrm[r0 + RMAP(ty,u)];
    #pragma unroll 1
    for (int v = 0; v < 8; v++)
      s += __expf(-(ni + nrm[c0 + CMAP(tx,v)] - 2.f * acc[u][v]) * (1.f/2048.f));
  }
  block_atomic_add(s * wgt, red, slots + 0);
}

__global__ __launch_bounds__(256) void k_spp_sqp(const float* __restrict__ stdn,
                                                 const float* __restrict__ stdsq,
                                                 const float* __restrict__ zrs,
                                                 const float* __restrict__ nrmz,
                                                 float* __restrict__ slots){
  __shared__ float sI[128*9], sJ[128*9], zI[128*9];
  __shared__ float qI[128], qJ[128], nI[128];
  __shared__ float red[4];
  const int r0 = blockIdx.y * 128, c0 = blockIdx.x * 128;
  const int t = threadIdx.x;
  if (t < 128){
    #pragma unroll
    for (int v = 0; v < 8; v++){
      sI[t*9+v] = stdn[(size_t)(r0+t)*NV + v];
      sJ[t*9+v] = stdn[(size_t)(c0+t)*NV + v];
      zI[t*9+v] = zrs[(size_t)(r0+t)*NV + v];
    }
    qI[t] = stdsq[r0+t]; qJ[t] = stdsq[c0+t]; nI[t] = nrmz[r0+t];
  }
  __syncthreads();
  const int tx = t & 15, ty = t >> 4;
  float spp = 0.f, sqp = 0.f;
  #pragma unroll 1
  for (int u = 0; u < 8; u++){
    int i = ty + 16*u;
    #pragma unroll 1
    for (int v = 0; v < 8; v++){
      int j = tx + 16*v;
      float dpp = 0.f, dqp = 0.f;
      #pragma unroll
      for (int k = 0; k < 8; k++){
        float sj = sJ[j*9+k];
        dpp += sI[i*9+k] * sj;
        dqp += zI[i*9+k] * sj;
      }
      spp += __expf(-(qI[i] + qJ[j] - 2.f*dpp) * (1.f/64.f));
      sqp += __expf(-(nI[i] + 32.f*qJ[j] - 2.f*dqp) * (1.f/2048.f));
    }
  }
  block_atomic_add(spp, red, slots + 1);
  block_atomic_add(sqp, red, slots + 2);
}

// ---------------- RBF Gram matrix build (K=32, fp32 out) ----------------
__global__ __launch_bounds__(256) void k_rbf(const float* __restrict__ Xr_,
                                             const float* __restrict__ Xc_,
                                             const float* __restrict__ nr,
                                             const float* __restrict__ nc,
                                             float lam, float* __restrict__ M){
  __shared__ float Xr[128 * 33];
  __shared__ float Xc[128 * 33];
  const int r0 = blockIdx.y * 128, c0 = blockIdx.x * 128;
  const int t = threadIdx.x;
  const int tx = t & 15, ty = t >> 4;
  const int lrow = t >> 1, lh = t & 1;
  {
    const float* pr = Xr_ + (size_t)(r0 + lrow) * DD + lh * 16;
    const float* pc = Xc_ + (size_t)(c0 + lrow) * DD + lh * 16;
    float* dr = &Xr[lrow * 33 + lh * 16];
    float* dc = &Xc[lrow * 33 + lh * 16];
    #pragma unroll
    for (int u = 0; u < 4; u++){
      float4 a = ((const float4*)pr)[u];
      dr[4*u+0]=a.x; dr[4*u+1]=a.y; dr[4*u+2]=a.z; dr[4*u+3]=a.w;
      float4 b = ((const float4*)pc)[u];
      dc[4*u+0]=b.x; dc[4*u+1]=b.y; dc[4*u+2]=b.z; dc[4*u+3]=b.w;
    }
  }
  __syncthreads();
  #pragma unroll 1
  for (int u = 0; u < 8; u++){
    const int gi = r0 + RMAP(ty,u);
    const float* xi = &Xr[RMAP(ty,u)*33];
    const float ni = nr[gi];
    float vals[8];
    #pragma unroll 1
    for (int v = 0; v < 8; v++){
      const int gj = c0 + CMAP(tx,v);
      const float* xj = &Xc[CMAP(tx,v)*33];
      float d = 0.f;
      #pragma unroll
      for (int k = 0; k < 32; k++) d += xi[k] * xj[k];
      float e = __expf(-(ni + nc[gj] - 2.f*d) * (1.f/32.f));
      if (gi == gj) e += lam;
      vals[v] = e;
    }
    float* pd = M + (size_t)gi * NN + c0 + tx*4;
    *(float4*)pd        = make_float4(vals[0], vals[1], vals[2], vals[3]);
    *(float4*)(pd + 64) = make_float4(vals[4], vals[5], vals[6], vals[7]);
  }
}

// ---------------- RBF Gram matrix build (K=32, bf16 out, no diag reg) ----------------
__global__ __launch_bounds__(256) void k_rbf16(const float* __restrict__ Xr_,
                                               const float* __restrict__ Xc_,
                                               const float* __restrict__ nr,
                                               const float* __restrict__ nc,
                                               ushort* __restrict__ Mh){
  __shared__ float Xr[128 * 33];
  __shared__ float Xc[128 * 33];
  const int r0 = blockIdx.y * 128, c0 = blockIdx.x * 128;
  const int t = threadIdx.x;
  const int tx = t & 15, ty = t >> 4;
  const int lrow = t >> 1, lh = t & 1;
  {
    const float* pr = Xr_ + (size_t)(r0 + lrow) * DD + lh * 16;
    const float* pc = Xc_ + (size_t)(c0 + lrow) * DD + lh * 16;
    float* dr = &Xr[lrow * 33 + lh * 16];
    float* dc = &Xc[lrow * 33 + lh * 16];
    #pragma unroll
    for (int u = 0; u < 4; u++){
      float4 a = ((const float4*)pr)[u];
      dr[4*u+0]=a.x; dr[4*u+1]=a.y; dr[4*u+2]=a.z; dr[4*u+3]=a.w;
      float4 b = ((const float4*)pc)[u];
      dc[4*u+0]=b.x; dc[4*u+1]=b.y; dc[4*u+2]=b.z; dc[4*u+3]=b.w;
    }
  }
  __syncthreads();
  #pragma unroll 1
  for (int u = 0; u < 8; u++){
    const int gi = r0 + RMAP(ty,u);
    const float* xi = &Xr[RMAP(ty,u)*33];
    const float ni = nr[gi];
    ushort vals[8];
    #pragma unroll 1
    for (int v = 0; v < 8; v++){
      const int gj = c0 + CMAP(tx,v);
      const float* xj = &Xc[CMAP(tx,v)*33];
      float d = 0.f;
      #pragma unroll
      for (int k = 0; k < 32; k++) d += xi[k] * xj[k];
      vals[v] = f2bf(__expf(-(ni + nc[gj] - 2.f*d) * (1.f/32.f)));
    }
    ushort* pd = Mh + (size_t)gi * NN + c0 + tx*4;
    *(ushort4*)pd        = make_ushort4(vals[0], vals[1], vals[2], vals[3]);
    *(ushort4*)(pd + 64) = make_ushort4(vals[4], vals[5], vals[6], vals[7]);
  }
}

// ---------------- fp32 -> bf16 (hi only; trace GEMMs run pure bf16) ----------------
__global__ __launch_bounds__(256) void k_split(const float* __restrict__ S,
                                               ushort* __restrict__ H){
  size_t i = ((size_t)blockIdx.x * 256 + threadIdx.x) * 4;
  float4 x = *(const float4*)(S + i);
  *(ushort4*)(H + i) = make_ushort4(f2bf(x.x), f2bf(x.y), f2bf(x.z), f2bf(x.w));
}

// ---------------- MFMA bf16 GEMM + fused RBF-trace epilogue(s) + fused tr(L*A) ----
__global__ __launch_bounds__(256) void k_mfma_tr(
    const ushort* __restrict__ Ah, const ushort* __restrict__ Bh,
    int sym, int doRed, int nepi,
    const float* e0xr, const float* e0xc, const float* e0nr, const float* e0nc, int s0, int rs0,
    const float* e1xr, const float* e1xc, const float* e1nr, const float* e1nc, int s1, int rs1,
    float* __restrict__ slots){
  __shared__ __align__(16) float shf[2*128*33 + 4];
  ushort* tAh = (ushort*)shf;
  ushort* tBh = tAh + 4096;
  float* red = shf + 2*128*33;
  int bi, bj;
  if (sym){ tri_map(blockIdx.x, bi, bj); } else { bi = blockIdx.y; bj = blockIdx.x; }
  const int r0 = bi * 128, c0 = bj * 128;
  const float wgt = (sym && bi != bj) ? 2.f : 1.f;
  const int t = threadIdx.x;
  const int L = t & 63, w = t >> 6;
  const int wr = w >> 1, wc = w & 1;
  const int lm = L & 15, quad = L >> 4;
  const int sch = (t & 3) * 8;

  f32x4 acc[4][4];
  #pragma unroll
  for (int i = 0; i < 4; i++)
    #pragma unroll
    for (int j = 0; j < 4; j++) acc[i][j] = (f32x4){0.f, 0.f, 0.f, 0.f};

  for (int ks = 0; ks < NN; ks += 32){
    #pragma unroll
    for (int p = 0; p < 2; p++){
      const int row = p*64 + (t >> 2);
      const size_t ga = (size_t)(r0 + row) * NN + ks + sch;
      const size_t gb = (size_t)(c0 + row) * NN + ks + sch;
      const int lo = row*32 + sch;
      stage16(Ah + ga, tAh + lo);
      stage16(Bh + gb, tBh + lo);
    }
    __syncthreads();
    bf16x8 ah[4], bh[4];
    #pragma unroll
    for (int i = 0; i < 4; i++){
      const int ao = (wr*64 + i*16 + lm)*32 + quad*8;
      const int bo = (wc*64 + i*16 + lm)*32 + quad*8;
      ah[i] = *(const bf16x8*)&tAh[ao];
      bh[i] = *(const bf16x8*)&tBh[bo];
    }
    #pragma unroll
    for (int i = 0; i < 4; i++)
      #pragma unroll
      for (int j = 0; j < 4; j++)
        acc[i][j] = __builtin_amdgcn_mfma_f32_16x16x32_bf16(ah[i], bh[j], acc[i][j], 0, 0, 0);
    __syncthreads();
  }

  float* Xr = shf;
  float* Xc = shf + 128*33;
  const int lrow = t >> 1, lh = t & 1;
  for (int e = 0; e < nepi; e++){
    const float* xr = e ? e1xr : e0xr;
    const float* xc = e ? e1xc : e0xc;
    const float* nr = e ? e1nr : e0nr;
    const float* nc = e ? e1nc : e0nc;
    const int slot = e ? s1 : s0;
    const int rslot = e ? rs1 : rs0;
    {
      const float* pr = xr + (size_t)(r0 + lrow) * DD + lh * 16;
      const float* pc = xc + (size_t)(c0 + lrow) * DD + lh * 16;
      float* dr = &Xr[lrow * 33 + lh * 16];
      float* dc = &Xc[lrow * 33 + lh * 16];
      #pragma unroll
      for (int u = 0; u < 4; u++){
        float4 a = ((const float4*)pr)[u];
        dr[4*u+0]=a.x; dr[4*u+1]=a.y; dr[4*u+2]=a.z; dr[4*u+3]=a.w;
        float4 b = ((const float4*)pc)[u];
        dc[4*u+0]=b.x; dc[4*u+1]=b.y; dc[4*u+2]=b.z; dc[4*u+3]=b.w;
      }
    }
    __syncthreads();
    float s = 0.f, s2 = 0.f;
    #pragma unroll 1
    for (int i = 0; i < 4; i++){
      #pragma unroll 1
      for (int rg = 0; rg < 4; rg++){
        const int rl = wr*64 + i*16 + quad*4 + rg;
        const float* xi = &Xr[rl*33];
        const float ni = nr[r0 + rl];
        #pragma unroll 1
        for (int j = 0; j < 4; j++){
          const int cl = wc*64 + j*16 + lm;
          const float* xj = &Xc[cl*33];
          float d = 0.f;
          #pragma unroll
          for (int k = 0; k < 32; k++) d = fmaf(xi[k], xj[k], d);
          const float Lval = __expf(-(ni + nc[c0 + cl] - 2.f*d) * (1.f/32.f));
          s += acc[i][j][rg] * Lval;
          if (doRed){
            const size_t o = (size_t)(r0 + rl) * NN + c0 + cl;
            s2 += bf2f(Ah[o]) * Lval;
          }
        }
      }
    }
    block_atomic_add(s * wgt, red, slots + slot);
    if (doRed) block_atomic_add(s2 * wgt, red, slots + rslot);
    __syncthreads();
  }
}

// ---------------- plain MFMA bf16 GEMM, bf16 store (V = B * QP^T-row layout) ----------
__global__ __launch_bounds__(256) void k_mfma_gemm(
    const ushort* __restrict__ Ah, const ushort* __restrict__ Bh,
    ushort* __restrict__ Dh){
  __shared__ __align__(16) ushort tAh[4096];
  __shared__ __align__(16) ushort tBh[4096];
  const int r0 = blockIdx.y * 128, c0 = blockIdx.x * 128;
  const int t = threadIdx.x;
  const int L = t & 63, w = t >> 6;
  const int wr = w >> 1, wc = w & 1;
  const int lm = L & 15, quad = L >> 4;
  const int sch = (t & 3) * 8;
  f32x4 acc[4][4];
  #pragma unroll
  for (int i = 0; i < 4; i++)
    #pragma unroll
    for (int j = 0; j < 4; j++) acc[i][j] = (f32x4){0.f, 0.f, 0.f, 0.f};
  for (int ks = 0; ks < NN; ks += 32){
    #pragma unroll
    for (int p = 0; p < 2; p++){
      const int row = p*64 + (t >> 2);
      const size_t ga = (size_t)(r0 + row) * NN + ks + sch;
      const size_t gb = (size_t)(c0 + row) * NN + ks + sch;
      const int lo = row*32 + sch;
      stage16(Ah + ga, tAh + lo);
      stage16(Bh + gb, tBh + lo);
    }
    __syncthreads();
    bf16x8 ah[4], bh[4];
    #pragma unroll
    for (int i = 0; i < 4; i++){
      const int ao = (wr*64 + i*16 + lm)*32 + quad*8;
      const int bo = (wc*64 + i*16 + lm)*32 + quad*8;
      ah[i] = *(const bf16x8*)&tAh[ao];
      bh[i] = *(const bf16x8*)&tBh[bo];
    }
    #pragma unroll
    for (int i = 0; i < 4; i++)
      #pragma unroll
      for (int j = 0; j < 4; j++)
        acc[i][j] = __builtin_amdgcn_mfma_f32_16x16x32_bf16(ah[i], bh[j], acc[i][j], 0, 0, 0);
    __syncthreads();
  }
  #pragma unroll
  for (int i = 0; i < 4; i++)
    #pragma unroll
    for (int j = 0; j < 4; j++)
      #pragma unroll
      for (int rg = 0; rg < 4; rg++){
        const int row = wr*64 + i*16 + quad*4 + rg;
        const int col = wc*64 + j*16 + lm;
        Dh[(size_t)(r0 + row) * NN + c0 + col] = f2bf(acc[i][j][rg]);
      }
}

// ---------------- fused GJ diag + panel (512 threads, grid 16 x 2mats) ----------------
__global__ __launch_bounds__(512) void k_gj_diagpanel(
    float* __restrict__ M0, float* __restrict__ M1,
    float* __restrict__ Pbuf, ushort* __restrict__ Pth, ushort* __restrict__ Ptl,
    float* __restrict__ Tf, ushort* __restrict__ Tth, ushort* __restrict__ Ttl,
    ushort* __restrict__ Chh, ushort* __restrict__ Chl, int kb){
  __shared__ float Ps[128 * 132];
  __shared__ float rowbuf[NB];
  __shared__ float colbuf[NB];
  __shared__ float Bs[2][16 * 132];
  const int mat = blockIdx.y;
  float* M = mat ? M1 : M0;
  float* P = Pbuf + (size_t)mat * NB * NB;
  ushort* Ph = Pth + (size_t)mat * NB * NB;
  ushort* Pl = Ptl + (size_t)mat * NB * NB;
  float* Tfm = Tf + (size_t)mat * NB * NN;
  ushort* Th = Tth + (size_t)mat * NN * NB;
  ushort* Tl = Ttl + (size_t)mat * NN * NB;
  ushort* Ch = Chh + (size_t)mat * NN * NB;
  ushort* Cl = Chl + (size_t)mat * NN * NB;
  const int k0 = kb * NB;
  const int t = threadIdx.x;
  // ---- register GJ diag (proven layout: r = t>>2, g = t&3, reg[32]) ----
  {
    const int r = t >> 2, g = t & 3;
    float reg[32];
    #pragma unroll
    for (int j = 0; j < 32; j++) reg[j] = M[(size_t)(k0 + r) * NN + k0 + g + 4*j];
    __syncthreads();
    #pragma unroll 1
    for (int jj = 0; jj < NB; jj++){
      if (r == jj){
        #pragma unroll
        for (int j = 0; j < 32; j++) rowbuf[g + 4*j] = reg[j];
      }
      if (g == (jj & 3)) colbuf[r] = reg[jj >> 2];
      __syncthreads();
      const float p = 1.0f / rowbuf[jj];
      if (r == jj){
        #pragma unroll
        for (int j = 0; j < 32; j++){
          const int c = g + 4*j;
          reg[j] = (c == jj) ? p : reg[j] * p;
        }
      } else {
        const float f = colbuf[r] * p;
        #pragma unroll
        for (int j = 0; j < 32; j++){
          const int c = g + 4*j;
          reg[j] = (c == jj) ? (-f) : fmaf(-f, rowbuf[c], reg[j]);
        }
      }
      __syncthreads();
    }
    #pragma unroll
    for (int j = 0; j < 32; j++){
      const int c = g + 4*j;
      Ps[r*132 + c] = reg[j];
    }
    if (blockIdx.x == 0){
      #pragma unroll
      for (int j = 0; j < 32; j++){
        const int c = g + 4*j;
        P[r * NB + c] = reg[j];
        ushort h = f2bf(reg[j]);
        Ph[(size_t)c * NB + r] = h;
        Pl[(size_t)c * NB + r] = f2bf(reg[j] - bf2f(h));
      }
    }
  }
  __syncthreads();
  // ---- panel GEMM: 2 j-tiles per block, one per 256-thread half ----
  const int half = t >> 8, tt = t & 255;
  const int j0 = blockIdx.x * 256 + half * 128;
  { // C split copy of M[:, kcol] panel (rows j0..j0+127) - pre-update values
    const int row = tt >> 1, hc = (tt & 1) * 64;
    const float* src = M + (size_t)(j0 + row) * NN + k0 + hc;
    ushort* dh = Ch + (size_t)(j0 + row) * NB + hc;
    ushort* dl = Cl + (size_t)(j0 + row) * NB + hc;
    #pragma unroll
    for (int u = 0; u < 16; u++){
      float4 v = ((const float4*)src)[u];
      ushort h0 = f2bf(v.x), h1 = f2bf(v.y), h2 = f2bf(v.z), h3 = f2bf(v.w);
      ((ushort4*)dh)[u] = make_ushort4(h0, h1, h2, h3);
      ((ushort4*)dl)[u] = make_ushort4(f2bf(v.x - bf2f(h0)), f2bf(v.y - bf2f(h1)),
                                       f2bf(v.z - bf2f(h2)), f2bf(v.w - bf2f(h3)));
    }
  }
  const int tx = tt & 15, ty = tt >> 4;
  float* myBs = Bs[half];
  float acc[8][8];
  #pragma unroll
  for (int u = 0; u < 8; u++)
    #pragma unroll
    for (int v = 0; v < 8; v++) acc[u][v] = 0.f;
  for (int ks = 0; ks < NB; ks += 16){
    {
      const int kkl = tt >> 4, c8 = (tt & 15) * 8;
      const float* pb = M + (size_t)(k0 + ks + kkl) * NN + j0 + c8;
      float4 b0 = ((const float4*)pb)[0];
      float4 b1 = ((const float4*)pb)[1];
      *(float4*)&myBs[kkl*132 + c8]     = b0;
      *(float4*)&myBs[kkl*132 + c8 + 4] = b1;
    }
    __syncthreads();
    #pragma unroll
    for (int kk = 0; kk < 16; kk++){
      float a[8], b[8];
      #pragma unroll
      for (int u = 0; u < 8; u++) a[u] = Ps[RMAP(ty,u)*132 + ks + kk];
      float4 b0 = *(const float4*)&myBs[kk*132 + tx*4];
      float4 b1 = *(const float4*)&myBs[kk*132 + tx*4 + 64];
      b[0]=b0.x; b[1]=b0.y; b[2]=b0.z; b[3]=b0.w;
      b[4]=b1.x; b[5]=b1.y; b[6]=b1.z; b[7]=b1.w;
      #pragma unroll
      for (int u = 0; u < 8; u++)
        #pragma unroll
        for (int v = 0; v < 8; v++) acc[u][v] += a[u] * b[v];
    }
    __syncthreads();
  }
  // write T fp32 (coalesced) + T transposed split
  #pragma unroll
  for (int u = 0; u < 8; u++){
    const int rr = RMAP(ty,u);
    float* pd = Tfm + (size_t)rr * NN + j0 + tx*4;
    *(float4*)pd        = make_float4(acc[u][0], acc[u][1], acc[u][2], acc[u][3]);
    *(float4*)(pd + 64) = make_float4(acc[u][4], acc[u][5], acc[u][6], acc[u][7]);
    #pragma unroll
    for (int v = 0; v < 8; v++){
      const int cc = j0 + CMAP(tx,v);
      float val = acc[u][v];
      ushort h = f2bf(val);
      Th[(size_t)cc * NB + rr] = h;
      Tl[(size_t)cc * NB + rr] = f2bf(val - bf2f(h));
    }
  }
}

// Trailing update (MFMA split-3) + chunked LDS-transpose epilogue (33.8 KB LDS -> 4 blk/CU)
__global__ __launch_bounds__(256) void k_gj_update(float* __restrict__ M0, float* __restrict__ M1,
    const float* __restrict__ Pbuf,
    const ushort* __restrict__ Pth, const ushort* __restrict__ Ptl,
    const float* __restrict__ Tf,
    const ushort* __restrict__ Tth, const ushort* __restrict__ Ttl,
    const ushort* __restrict__ Chh, const ushort* __restrict__ Chl, int kb){
  __shared__ __align__(16) float shchunk[64 * 132];   // 33.8 KB; staging aliased below (32 KB)
  ushort* tAh = (ushort*)shchunk;
  ushort* tAl = tAh + 4096;
  ushort* tBh = tAl + 4096;
  ushort* tBl = tBh + 4096;
  const int mat = blockIdx.z;
  float* M = mat ? M1 : M0;
  const float* P = Pbuf + (size_t)mat * NB * NB;
  const ushort* Ph = Pth + (size_t)mat * NB * NB;
  const ushort* Pl = Ptl + (size_t)mat * NB * NB;
  const float* Tfm = Tf + (size_t)mat * NB * NN;
  const ushort* Th = Tth + (size_t)mat * NN * NB;
  const ushort* Tl = Ttl + (size_t)mat * NN * NB;
  const ushort* Ch = Chh + (size_t)mat * NN * NB;
  const ushort* Cl = Chl + (size_t)mat * NN * NB;
  const int jb = blockIdx.x, ib = blockIdx.y;
  const int k0 = kb * NB, i0 = ib * NB, j0 = jb * NB;
  const int t = threadIdx.x;
  if (ib == kb){
    const int row = t >> 1, half = (t & 1) * 64;
    float* dst = M + (size_t)(k0 + row) * NN + j0 + half;
    if (jb == kb){
      const float* src = P + (size_t)row * NB + half;
      #pragma unroll
      for (int u = 0; u < 16; u++) ((float4*)dst)[u] = ((const float4*)src)[u];
    } else {
      const float* src = Tfm + (size_t)row * NN + j0 + half;
      #pragma unroll
      for (int u = 0; u < 16; u++) ((float4*)dst)[u] = ((const float4*)src)[u];
    }
    return;
  }
  const int L = t & 63, w = t >> 6;
  const int wr = w >> 1, wc = w & 1;
  const int lm = L & 15, quad = L >> 4;
  const int sch = (t & 3) * 8;
  const ushort* Bh = (jb == kb) ? Ph : (Th + (size_t)j0 * NB);
  const ushort* Bl = (jb == kb) ? Pl : (Tl + (size_t)j0 * NB);
  const ushort* Ahp = Ch + (size_t)i0 * NB;
  const ushort* Alp = Cl + (size_t)i0 * NB;
  f32x4 acc[4][4];
  #pragma unroll
  for (int i = 0; i < 4; i++)
    #pragma unroll
    for (int j = 0; j < 4; j++) acc[i][j] = (f32x4){0.f, 0.f, 0.f, 0.f};
  for (int ks = 0; ks < NB; ks += 32){
    #pragma unroll
    for (int p = 0; p < 2; p++){
      const int row = p*64 + (t >> 2);
      const size_t ga = (size_t)row * NB + ks + sch;
      const int lo = row*32 + sch;
      stage16(Ahp + ga, tAh + lo);
      stage16(Alp + ga, tAl + lo);
      stage16(Bh + ga, tBh + lo);
      stage16(Bl + ga, tBl + lo);
    }
    __syncthreads();
    bf16x8 ah[4], al[4], bh[4], bl[4];
    #pragma unroll
    for (int i = 0; i < 4; i++){
      const int ao = (wr*64 + i*16 + lm)*32 + quad*8;
      const int bo = (wc*64 + i*16 + lm)*32 + quad*8;
      ah[i] = *(const bf16x8*)&tAh[ao];
      al[i] = *(const bf16x8*)&tAl[ao];
      bh[i] = *(const bf16x8*)&tBh[bo];
      bl[i] = *(const bf16x8*)&tBl[bo];
    }
    #pragma unroll
    for (int i = 0; i < 4; i++)
      #pragma unroll
      for (int j = 0; j < 4; j++){
        acc[i][j] = __builtin_amdgcn_mfma_f32_16x16x32_bf16(ah[i], bh[j], acc[i][j], 0, 0, 0);
        acc[i][j] = __builtin_amdgcn_mfma_f32_16x16x32_bf16(ah[i], bl[j], acc[i][j], 0, 0, 0);
        acc[i][j] = __builtin_amdgcn_mfma_f32_16x16x32_bf16(al[i], bh[j], acc[i][j], 0, 0, 0);
      }
    __syncthreads();
  }
  // chunked transpose: 2 passes of 64 rows through 33.8 KB LDS, coalesced float4 RMW
  const int rloc = t >> 2, cg = (t & 3) * 4;
  const int jc0 = (jb == kb) ? k0 : j0;
  #pragma unroll 1
  for (int hp = 0; hp < 2; hp++){
    if (wr == hp){
      #pragma unroll
      for (int i = 0; i < 4; i++)
        #pragma unroll
        for (int j = 0; j < 4; j++)
          #pragma unroll
          for (int rg = 0; rg < 4; rg++){
            const int row = i*16 + quad*4 + rg;       // local 0..63
            const int col = wc*64 + j*16 + lm;
            shchunk[row*132 + col] = acc[i][j][rg];
          }
    }
    __syncthreads();
    float* pm = M + (size_t)(i0 + hp*64 + rloc) * NN + jc0;
    if (jb == kb){
      #pragma unroll
      for (int c = 0; c < 8; c++){
        const int col = cg + 16*c;
        float4 v = *(float4*)&shchunk[rloc*132 + col];
        *(float4*)(pm + col) = make_float4(-v.x, -v.y, -v.z, -v.w);
      }
    } else {
      #pragma unroll
      for (int c = 0; c < 8; c++){
        const int col = cg + 16*c;
        float4 v = *(float4*)&shchunk[rloc*132 + col];
        float4 m = *(float4*)(pm + col);
        m.x -= v.x; m.y -= v.y; m.z -= v.z; m.w -= v.w;
        *(float4*)(pm + col) = m;
      }
    }
    __syncthreads();
  }
}

// ---------------- final combine ----------------
__global__ void k_combine(const float* __restrict__ slots, float* __restrict__ out){
  if (threadIdx.x == 0 && blockIdx.x == 0){
    const double invN2 = 1.0 / ((double)NN * (double)NN);
    double term1 = ((double)slots[0] + (double)slots[1] - 2.0 * (double)slots[2]) * invN2;
    double pairs = 0.0;
    for (int p = 0; p < 3; p++){
      const float* s = slots + 4 + 5 * p;
      pairs += ((double)s[0] - 0.2 * (double)s[1] + (double)s[2] - 0.2 * (double)s[3] - 2.0 * (double)s[4]);
    }
    out[0] = (float)(1.0 * term1 + 500.0 * pairs * invN2);
    out[1] = (float)((double)slots[3] / (2.0 * (double)NN));
  }
}

// ---------------- host ----------------
extern "C" void kernel_launch(void* const* d_in, const int* in_sizes, int n_in,
                              void* d_out, int out_size, void* d_ws, size_t ws_size,
                              hipStream_t stream){
  const float* x    = (const float*)d_in[0];
  const float* z    = (const float*)d_in[1];
  const float* zz   = (const float*)d_in[2];
  const float* xx   = (const float*)d_in[3];
  const float* stdn = (const float*)d_in[4];
  float* out = (float*)d_out;
  float* ws  = (float*)d_ws;

  const size_t NN2 = (size_t)NN * NN;
  float* R0 = ws;
  float* R1 = R0 + NN2;
  float* R2 = R1 + NN2;
  float* PanelF = R2 + NN2;
  ushort* Tth = (ushort*)PanelF;                       // 2 MB
  ushort* Ttl = Tth + 2 * (size_t)NB * NN;
  ushort* Chh = Ttl + 2 * (size_t)NB * NN;
  ushort* Chl = Chh + 2 * (size_t)NB * NN;             // panels total 8 MB
  float* Tf   = (float*)(Chl + 2 * (size_t)NB * NN);   // 4 MB fp32 T (2 mats)
  float* Pb   = Tf + 2 * (size_t)NB * NN;              // fp32 P (2 mats)
  ushort* Pth = (ushort*)(Pb + 2 * (size_t)NB * NB);
  ushort* Ptl = Pth + 2 * (size_t)NB * NB;
  float* slots= (float*)(Ptl + 2 * (size_t)NB * NB);
  float* stdsq= slots + 32;
  float* zrs  = stdsq + NN;
  float* nzz  = zrs + (size_t)NN * NV;
  float* nz8  = nzz + (size_t)NV * NN;
  float* nrmz = nz8 + (size_t)NV * NN;

  ushort* R0h = (ushort*)R0;   // B hi (bf16)
  ushort* R2h = (ushort*)R2;   // A hi (bf16)
  ushort* Vh  = (ushort*)R1;   // V hi (bf16, lower half of R1)
  ushort* QPh = Vh + NN2;      // Kqp bf16 (upper half of R1)

  dim3 g32(NBLK, NBLK);

  k_zero<<<1, 64, 0, stream>>>(slots, 32);
  k_norms<<<(NN * NV) / 256, 256, 0, stream>>>(z, zz, stdn, stdsq, zrs, nzz, nz8);
  k_rownorm<<<NN / 256, 256, 0, stream>>>(nz8, nrmz);
  k_nll<<<1024, 256, 0, stream>>>(x, xx, slots);
  k_sqq<<<NTRI, 256, 0, stream>>>(z, nrmz, slots);
  k_spp_sqp<<<g32, 256, 0, stream>>>(stdn, stdsq, zrs, nrmz, slots);

  const float* zz0 = zz;            const float* z0 = z;
  const float* zz1 = zz + VD;       const float* z1 = z + VD;
  const float* nzz0 = nzz;          const float* nz0 = nz8;
  const float* nzz1 = nzz + NN;     const float* nz1 = nz8 + NN;

  for (int b = 1; b <= 2; b++){
    const float* zzb = zz + b*VD;  const float* nzzb = nzz + (size_t)b*NN;
    const float* zb  = z + b*VD;   const float* nzb  = nz8 + (size_t)b*NN;
    k_rbf<<<g32, 256, 0, stream>>>(zzb, zzb, nzzb, nzzb, 0.2f, R0);
    k_rbf<<<g32, 256, 0, stream>>>(zb,  zb,  nzb,  nzb,  0.2f, R1);
    for (int kb = 0; kb < NBLK; kb++){
      k_gj_diagpanel<<<dim3(16, 2), 512, 0, stream>>>(R0, R1, Pb, Pth, Ptl,
                                                      Tf, Tth, Ttl, Chh, Chl, kb);
      k_gj_update<<<dim3(NBLK, NBLK, 2), 256, 0, stream>>>(R0, R1, Pb, Pth, Ptl,
                                                           Tf, Tth, Ttl, Chh, Chl, kb);
    }
    // bf16 casts: A -> R2h, B -> R0h (B fp32 in R1 dead after)
    k_split<<<16384, 256, 0, stream>>>(R0, R2h);
    k_split<<<16384, 256, 0, stream>>>(R1, R0h);
    // Kqp bf16 precompute: QP[n][l] = k(zz_n, z_l), into upper half of R1
    k_rbf16<<<g32, 256, 0, stream>>>(zzb, zb, nzzb, nzb, QPh);
    // V = B * QP^T (plain bf16 GEMM); dest Vh (lower half of R1)
    k_mfma_gemm<<<g32, 256, 0, stream>>>(R0h, QPh, Vh);
    // trace GEMMs (pure bf16) with fused tr(L*A) reduction
    if (b == 1){
      k_mfma_tr<<<NTRI, 256, 0, stream>>>(R2h, R2h, 1, 1, 1,
                                          zz0, zz0, nzz0, nzz0, 5, 4,
                                          nullptr, nullptr, nullptr, nullptr, 0, 0, slots);
      k_mfma_tr<<<NTRI, 256, 0, stream>>>(R0h, R0h, 1, 1, 1,
                                          z0, z0, nz0, nz0, 7, 6,
                                          nullptr, nullptr, nullptr, nullptr, 0, 0, slots);
      k_mfma_tr<<<g32, 256, 0, stream>>>(R2h, Vh, 0, 0, 1,
                                         zz0, z0, nzz0, nz0, 8, 0,
                                         nullptr, nullptr, nullptr, nullptr, 0, 0, slots);
    } else {
      k_mfma_tr<<<NTRI, 256, 0, stream>>>(R2h, R2h, 1, 1, 2,
                                          zz1, zz1, nzz1, nzz1, 10, 9,
                                          zz0, zz0, nzz0, nzz0, 15, 14, slots);
      k_mfma_tr<<<NTRI, 256, 0, stream>>>(R0h, R0h, 1, 1, 2,
                                          z1, z1, nz1, nz1, 12, 11,
                                          z0, z0, nz0, nz0, 17, 16, slots);
      k_mfma_tr<<<g32, 256, 0, stream>>>(R2h, Vh, 0, 0, 2,
                                         zz1, z1, nzz1, nz1, 13, 0,
                                         zz0, z0, nzz0, nz0, 18, 0, slots);
    }
  }
  k_combine<<<1, 1, 0, stream>>>(slots, out);
}